// Round 6
// baseline (249.469 us; speedup 1.0000x reference)
//
#include <hip/hip_runtime.h>
#include <hip/hip_fp16.h>

// MHA with softmax over HEADS axis. R13: barrier-free wave-independent
// attn_ctx. R7/R9/R12 all plateau 52-56us despite removing Pl, halving FETCH,
// deepening prefetch -> the invariant is the per-iter barrier lockstep. Now:
// wave-private dbuf K staging (8KB/wave, no s_barrier anywhere in the loop),
// V + IDn direct-to-register b128 prefetched one iter ahead, single counted
// vmcnt(10) per iter (drain target always has >=10 younger ops -> robust),
// IDn stored j-permuted by attn_denom (same pi as Vt) so one f16x8 covers
// both ni sub-tiles. T5 setprio around MFMA cluster (independent-wave regime).

typedef _Float16 f16;
typedef _Float16 f16x4 __attribute__((ext_vector_type(4)));
typedef _Float16 f16x8 __attribute__((ext_vector_type(8)));
typedef float    f32x4 __attribute__((ext_vector_type(4)));

#define S_LEN 2048
#define DIM   1024
#define NH    16
#define DK    64
// exp(s * 0.125) = exp2(s * log2(e)/8)
#define EXP2K 0.1803368801111244f

#define MFMA(a, b, c) __builtin_amdgcn_mfma_f32_16x16x32_f16(a, b, c, 0, 0, 0)

#define VM_WAIT0   asm volatile("s_waitcnt vmcnt(0)" ::: "memory")
#define VM_WAIT6   asm volatile("s_waitcnt vmcnt(6)" ::: "memory")
#define VM_WAIT10  asm volatile("s_waitcnt vmcnt(10)" ::: "memory")
#define LGKM_WAIT0 asm volatile("s_waitcnt lgkmcnt(0)" ::: "memory")
#define WG_BARRIER asm volatile("s_barrier" ::: "memory")

typedef __attribute__((address_space(1))) void g_void;
typedef __attribute__((address_space(3))) void l_void;

static __device__ __forceinline__ void gload_lds16(const void* g, void* l) {
  __builtin_amdgcn_global_load_lds((g_void*)g, (l_void*)l, 16, 0, 0);
}

static __device__ __forceinline__ float exp_s(float s) {
  return __builtin_amdgcn_exp2f(s * EXP2K);  // identical in denom & ctx
}

// ---------------------------------------------------------------- merged cvt fp32->f16
__global__ __launch_bounds__(256) void cvt_all(
    const float* __restrict__ q, const float* __restrict__ k, const float* __restrict__ v,
    const float* __restrict__ Wq, const float* __restrict__ Wk, const float* __restrict__ Wv,
    const float* __restrict__ Wo, f16* __restrict__ qh, f16* __restrict__ kh,
    f16* __restrict__ vh, f16* __restrict__ wqh, f16* __restrict__ wkh,
    f16* __restrict__ wvh, f16* __restrict__ woh) {
  const size_t M = 1048576;
  const int seg = blockIdx.y;
  const float* src;
  f16* dst;
  switch (seg) {
    case 0: src = q;      dst = qh;      break;
    case 1: src = q + M;  dst = qh + M;  break;
    case 2: src = k;      dst = kh;      break;
    case 3: src = k + M;  dst = kh + M;  break;
    case 4: src = v;      dst = vh;      break;
    case 5: src = v + M;  dst = vh + M;  break;
    case 6: src = Wq;     dst = wqh;     break;
    case 7: src = Wk;     dst = wkh;     break;
    case 8: src = Wv;     dst = wvh;     break;
    default: src = Wo;    dst = woh;     break;
  }
  int i = blockIdx.x * 256 + threadIdx.x;
  float4 vv = ((const float4*)src)[i];
  f16x4 o = {(f16)vv.x, (f16)vv.y, (f16)vv.z, (f16)vv.w};
  ((f16x4*)dst)[i] = o;
}

__global__ __launch_bounds__(256) void cvt_f32_f16(const float* __restrict__ src,
                                                   f16* __restrict__ dst, int n4) {
  int i = blockIdx.x * 256 + threadIdx.x;
  if (i < n4) {
    float4 v = ((const float4*)src)[i];
    f16x4 o = {(f16)v.x, (f16)v.y, (f16)v.z, (f16)v.w};
    ((f16x4*)dst)[i] = o;
  }
}

// ---------------------------------------------------------------- pipelined 128x64 GEMM core
static __device__ __forceinline__ void gemm32_core(const f16* __restrict__ X,
                                                   const f16* __restrict__ W,
                                                   int k0, int k1, int bm, int bn,
                                                   f16* As, f16* Bs,
                                                   f32x4 (&acc)[4][2]) {
  const int tid = threadIdx.x;
  const int wv = tid >> 6;
  const int lane = tid & 63;
  const int qd = lane >> 4;
  const int l16 = lane & 15;
  const int wm = (wv & 1) * 64;
  const int wn = (wv >> 1) * 32;
  const int lr4 = lane >> 2, lc4 = lane & 3;

  const f16* gA = X + (size_t)(bm + wv * 32 + lr4) * DIM + k0 + lc4 * 8;
  const f16* gB = W + (size_t)(bn + wv * 16 + lr4) * DIM + k0 + lc4 * 8;
  const int np = (k1 - k0) >> 5;

  // prologue: period 0 into buf 0
  gload_lds16(gA, As + (wv * 32) * 32);
  gload_lds16(gA + 16 * DIM, As + (wv * 32 + 16) * 32);
  gload_lds16(gB, Bs + (wv * 16) * 32);

#pragma unroll 2
  for (int t = 0; t < np; t++) {
    const int buf = t & 1;
    VM_WAIT0;
    WG_BARRIER;
    if (t + 1 < np) {
      const f16* gA1 = gA + (t + 1) * 32;
      const f16* gB1 = gB + (t + 1) * 32;
      f16* dA = As + (buf ^ 1) * (128 * 32);
      f16* dB = Bs + (buf ^ 1) * (64 * 32);
      gload_lds16(gA1, dA + (wv * 32) * 32);
      gload_lds16(gA1 + 16 * DIM, dA + (wv * 32 + 16) * 32);
      gload_lds16(gB1, dB + (wv * 16) * 32);
    }
    const f16* A = As + buf * (128 * 32);
    const f16* B = Bs + buf * (64 * 32);
    f16x8 bf[2];
#pragma unroll
    for (int ni = 0; ni < 2; ni++)
      bf[ni] = *(const f16x8*)&B[(wn + ni * 16 + l16) * 32 + qd * 8];
#pragma unroll
    for (int mi = 0; mi < 4; mi++) {
      f16x8 af = *(const f16x8*)&A[(wm + mi * 16 + l16) * 32 + qd * 8];
#pragma unroll
      for (int ni = 0; ni < 2; ni++)
        acc[mi][ni] = MFMA(af, bf[ni], acc[mi][ni]);
    }
  }
}

// ---------------------------------------------------------------- merged QKV proj
__global__ __launch_bounds__(256) void gemm_qkv(
    const f16* __restrict__ X0, const f16* __restrict__ X1, const f16* __restrict__ X2,
    const f16* __restrict__ W0, const f16* __restrict__ W1, const f16* __restrict__ W2,
    const float* __restrict__ b0, const float* __restrict__ b1, const float* __restrict__ b2,
    f16* __restrict__ o0, f16* __restrict__ o1, f16* __restrict__ o2) {
  __shared__ __align__(16) f16 As[2 * 128 * 32];
  __shared__ __align__(16) f16 Bs[2 * 64 * 32];
  const int z = blockIdx.z;
  const f16* X = z == 0 ? X0 : z == 1 ? X1 : X2;
  const f16* W = z == 0 ? W0 : z == 1 ? W1 : W2;
  const float* bias = z == 0 ? b0 : z == 1 ? b1 : b2;
  f16* outh = z == 0 ? o0 : z == 1 ? o1 : o2;

  const int bm = blockIdx.y * 128, bn = blockIdx.x * 64;
  f32x4 acc[4][2];
#pragma unroll
  for (int a = 0; a < 4; a++)
#pragma unroll
    for (int b = 0; b < 2; b++) acc[a][b] = (f32x4){0.f, 0.f, 0.f, 0.f};

  gemm32_core(X, W, 0, DIM, bm, bn, As, Bs, acc);

  const int tid = threadIdx.x;
  const int wv = tid >> 6, lane = tid & 63;
  const int qd = lane >> 4, l16 = lane & 15;
  const int wm = (wv & 1) * 64, wn = (wv >> 1) * 32;
#pragma unroll
  for (int mi = 0; mi < 4; mi++) {
#pragma unroll
    for (int ni = 0; ni < 2; ni++) {
      const int gm = bm + wm + mi * 16 + qd * 4;
      const int gn = bn + wn + ni * 16 + l16;
      const float bs = bias[gn];
      if (z == 2) {
        f16x4 o = {(f16)(acc[mi][ni][0] + bs), (f16)(acc[mi][ni][1] + bs),
                   (f16)(acc[mi][ni][2] + bs), (f16)(acc[mi][ni][3] + bs)};
        // Vt stored j-PERMUTED within each 32-block: storage[pi(j)] = V[j],
        // pi(gm) = (gm&~31) + ((gm>>2)&3)*8 + ((gm>>4)&1)*4 + (gm&3).
        const int pj = (gm & ~31) + ((gm >> 2) & 3) * 8 + ((gm >> 4) & 1) * 4;
        *(f16x4*)&outh[(size_t)gn * S_LEN + pj] = o;  // Vt[d][perm j]
      } else {
#pragma unroll
        for (int r = 0; r < 4; r++)
          outh[(size_t)(gm + r) * DIM + gn] = (f16)(acc[mi][ni][r] + bs);
      }
    }
  }
}

// ---------------------------------------------------------------- out GEMM 128x64, splitK2
__global__ __launch_bounds__(256) void gemm_out(const f16* __restrict__ X,
                                                const f16* __restrict__ W,
                                                const float* __restrict__ bias,
                                                float* __restrict__ outf) {
  __shared__ __align__(16) f16 As[2 * 128 * 32];
  __shared__ __align__(16) f16 Bs[2 * 64 * 32];
  const int z = blockIdx.z;
  const int bm = blockIdx.y * 128, bn = blockIdx.x * 64;
  f32x4 acc[4][2];
#pragma unroll
  for (int a = 0; a < 4; a++)
#pragma unroll
    for (int b = 0; b < 2; b++) acc[a][b] = (f32x4){0.f, 0.f, 0.f, 0.f};

  gemm32_core(X, W, z * (DIM / 2), (z + 1) * (DIM / 2), bm, bn, As, Bs, acc);

  const int tid = threadIdx.x;
  const int wv = tid >> 6, lane = tid & 63;
  const int qd = lane >> 4, l16 = lane & 15;
  const int wm = (wv & 1) * 64, wn = (wv >> 1) * 32;
#pragma unroll
  for (int mi = 0; mi < 4; mi++) {
#pragma unroll
    for (int ni = 0; ni < 2; ni++) {
      const int gm = bm + wm + mi * 16 + qd * 4;
      const int gn = bn + wn + ni * 16 + l16;
      const float bs = z == 0 ? bias[gn] : 0.f;
#pragma unroll
      for (int r = 0; r < 4; r++)
        atomicAdd(&outf[(size_t)(gm + r) * DIM + gn], acc[mi][ni][r] + bs);
    }
  }
}

// ---------------------------------------------------------------- pass A: IDn = 1/sum_h exp
// 64x64 tile, grid 1024. IDn now stored j-PERMUTED (same pi as Vt) so attn_ctx
// reads one f16x8 covering both ni sub-tiles, elementwise-aligned with P.
__global__ __launch_bounds__(256) void attn_denom(const f16* __restrict__ Qp,
                                                  const f16* __restrict__ Kp,
                                                  f16* __restrict__ IDn) {
  __shared__ __align__(16) f16 Qs[2][2][64 * 32];  // [buf][kk][row][32]
  __shared__ __align__(16) f16 Ks[2][2][64 * 32];
  const int tid = threadIdx.x;
  const int wv = tid >> 6;
  const int lane = tid & 63;
  const int qd = lane >> 4;
  const int l16 = lane & 15;
  const int wm = (wv & 1) * 32, wn = (wv >> 1) * 32;
  const int bi = blockIdx.y * 64, bj = blockIdx.x * 64;
  const int lr4 = lane >> 2, lc4 = lane & 3;
  const int kkw = wv & 1;
  const int q0 = (wv >> 1) * 2;

  f32x4 dsum[2][2];
#pragma unroll
  for (int a = 0; a < 2; a++)
#pragma unroll
    for (int b = 0; b < 2; b++) dsum[a][b] = (f32x4){0.f, 0.f, 0.f, 0.f};

  // prologue: head 0 -> buf 0
  {
    const f16* gq = Qp + (size_t)(bi + q0 * 16 + lr4) * DIM + kkw * 32 + lc4 * 8;
    const f16* gk = Kp + (size_t)(bj + q0 * 16 + lr4) * DIM + kkw * 32 + lc4 * 8;
#pragma unroll
    for (int t = 0; t < 2; t++) {
      gload_lds16(gq + (size_t)t * 16 * DIM, &Qs[0][kkw][(q0 + t) * 16 * 32]);
      gload_lds16(gk + (size_t)t * 16 * DIM, &Ks[0][kkw][(q0 + t) * 16 * 32]);
    }
  }

#pragma unroll 2
  for (int h = 0; h < NH; h++) {
    const int buf = h & 1;
    VM_WAIT0;
    WG_BARRIER;
    if (h + 1 < NH) {
      const f16* gq = Qp + (size_t)(bi + q0 * 16 + lr4) * DIM + (h + 1) * DK + kkw * 32 + lc4 * 8;
      const f16* gk = Kp + (size_t)(bj + q0 * 16 + lr4) * DIM + (h + 1) * DK + kkw * 32 + lc4 * 8;
#pragma unroll
      for (int t = 0; t < 2; t++) {
        gload_lds16(gq + (size_t)t * 16 * DIM, &Qs[buf ^ 1][kkw][(q0 + t) * 16 * 32]);
        gload_lds16(gk + (size_t)t * 16 * DIM, &Ks[buf ^ 1][kkw][(q0 + t) * 16 * 32]);
      }
    }

#pragma unroll
    for (int mi = 0; mi < 2; mi++) {
      f16x8 af0 = *(const f16x8*)&Qs[buf][0][(wm + mi * 16 + l16) * 32 + qd * 8];
      f16x8 af1 = *(const f16x8*)&Qs[buf][1][(wm + mi * 16 + l16) * 32 + qd * 8];
#pragma unroll
      for (int ni = 0; ni < 2; ni++) {
        f16x8 bf0 = *(const f16x8*)&Ks[buf][0][(wn + ni * 16 + l16) * 32 + qd * 8];
        f16x8 bf1 = *(const f16x8*)&Ks[buf][1][(wn + ni * 16 + l16) * 32 + qd * 8];
        f32x4 s = {0.f, 0.f, 0.f, 0.f};
        s = MFMA(af0, bf0, s);  // kk order identical to attn_ctx
        s = MFMA(af1, bf1, s);
#pragma unroll
        for (int r = 0; r < 4; r++) dsum[mi][ni][r] += exp_s(s[r]);
      }
    }
  }
#pragma unroll
  for (int mi = 0; mi < 2; mi++)
#pragma unroll
    for (int ni = 0; ni < 2; ni++)
#pragma unroll
      for (int r = 0; r < 4; r++) {
        const int gi = bi + wm + mi * 16 + qd * 4 + r;
        const int gj = bj + wn + ni * 16 + l16;
        // j-permuted store (same pi as Vt): IDnP[pi(gj)] = 1/dsum(gj)
        const int pj = (gj & ~31) + ((gj >> 2) & 3) * 8 + ((gj >> 4) & 1) * 4 + (gj & 3);
        IDn[(size_t)gi * S_LEN + pj] = (f16)(1.f / dsum[mi][ni][r]);
      }
}

// ---------------------------------------------------------------- pass B: ctx
// grid (S/128, NH, 4), XCD-remapped. Barrier-FREE: each wave owns i-sub 32,
// private dbuf K LDS (2x4KB), V+IDnP direct-to-reg b128 prefetched 1 iter
// ahead, K gloads 2 iters ahead, one vmcnt(10) per iter (K(t+1) always has
// >=10 younger ops -> drain guaranteed even with spills). No s_barrier.
__global__ __launch_bounds__(256, 4) void attn_ctx(const f16* __restrict__ Qp,
                                                   const f16* __restrict__ Kp,
                                                   const f16* __restrict__ Vt,
                                                   const f16* __restrict__ IDn,
                                                   float* __restrict__ Cp) {
  __shared__ __align__(16) f16 Ks[4][2][2][16 * 16 * 4];  // [wv][buf][kk][32j][32dk]
  const int tid = threadIdx.x;
  const int wv = tid >> 6;
  const int lane = tid & 63;
  const int qd = lane >> 4;
  const int l16 = lane & 15;
  // XCD-aware remap (R12-verified): contiguous 128-block chunks per XCD.
  const int flat = blockIdx.x + (blockIdx.y << 4) + (blockIdx.z << 8);
  const int nf = ((flat & 7) << 7) + (flat >> 3);
  const int h = (nf >> 4) & 15;
  const int iw = (nf & 15) * 128 + wv * 32;
  const int jb = (nf >> 8) * 512;
  const int lr4 = lane >> 2, lc4 = lane & 3;

  // Q fragments (B-operand of swapped QK^T)
  f16x8 aq[2][2];
#pragma unroll
  for (int mi = 0; mi < 2; mi++)
#pragma unroll
    for (int kk = 0; kk < 2; kk++)
      aq[mi][kk] = *(const f16x8*)(Qp + (size_t)(iw + mi * 16 + l16) * DIM +
                                   h * DK + kk * 32 + qd * 8);

  f32x4 acc[2][4];
#pragma unroll
  for (int a = 0; a < 2; a++)
#pragma unroll
    for (int b = 0; b < 4; b++) acc[a][b] = (f32x4){0.f, 0.f, 0.f, 0.f};

  f16x8 vf[4];      // V fragments for current iter (loaded 1 iter ahead)
  f16x8 idnp[2];    // permuted-IDn fragments, elementwise aligned with P

  const f16* kbase = Kp + (size_t)jb * DIM + h * DK;
  const f16* vbase = Vt + (size_t)h * DK * S_LEN + jb;
  const f16* ibase = IDn + (size_t)iw * S_LEN + jb;

  // issue 4 gload_lds for K(tile tt) into wave-private buf
  auto issueK = [&](int tt, int buf) {
    f16* dst = &Ks[wv][buf][0][0];
    const f16* src = kbase + (size_t)(tt * 32 + lr4) * DIM + lc4 * 8;
#pragma unroll
    for (int kk = 0; kk < 2; kk++)
#pragma unroll
      for (int r0 = 0; r0 < 2; r0++)
        gload_lds16(src + (size_t)(r0 * 16) * DIM + kk * 32,
                    dst + kk * 1024 + r0 * 16 * 32);
  };
  // register loads for tile tt: 4 V b128 + 2 IDnP b128
  auto loadVI = [&](int tt) {
#pragma unroll
    for (int nd = 0; nd < 4; nd++)
      vf[nd] = *(const f16x8*)(vbase + (size_t)(nd * 16 + l16) * S_LEN + tt * 32 + qd * 8);
#pragma unroll
    for (int mi = 0; mi < 2; mi++)
      idnp[mi] = *(const f16x8*)(ibase + (size_t)(mi * 16 + l16) * S_LEN + tt * 32 + qd * 8);
  };
  // compute tile (K from buf, V/IDnP from regs)
  auto body = [&](int buf) {
    f16x8 bk[2][2];
#pragma unroll
    for (int ni = 0; ni < 2; ni++)
#pragma unroll
      for (int kk = 0; kk < 2; kk++)
        bk[ni][kk] = *(const f16x8*)&Ks[wv][buf][kk][(ni * 16 + l16) * 32 + qd * 8];
    __builtin_amdgcn_s_setprio(1);
    f16x8 pa[2];
#pragma unroll
    for (int mi = 0; mi < 2; mi++) {
      f32x4 st0 = {0.f, 0.f, 0.f, 0.f};
      f32x4 st1 = {0.f, 0.f, 0.f, 0.f};
      st0 = MFMA(bk[0][0], aq[mi][0], st0);  // kk order identical to attn_denom
      st0 = MFMA(bk[0][1], aq[mi][1], st0);
      st1 = MFMA(bk[1][0], aq[mi][0], st1);
      st1 = MFMA(bk[1][1], aq[mi][1], st1);
      f16x8 p;
#pragma unroll
      for (int r = 0; r < 4; r++)
        p[r] = (f16)(exp_s(st0[r]) * (float)idnp[mi][r]);
#pragma unroll
      for (int r = 0; r < 4; r++)
        p[4 + r] = (f16)(exp_s(st1[r]) * (float)idnp[mi][4 + r]);
      pa[mi] = p;
    }
#pragma unroll
    for (int mi = 0; mi < 2; mi++)
#pragma unroll
      for (int nd = 0; nd < 4; nd++)
        acc[mi][nd] = MFMA(pa[mi], vf[nd], acc[mi][nd]);
    __builtin_amdgcn_s_setprio(0);
  };

  // prologue: K(0),K(1) in flight, V/IDn(0) in flight
  issueK(0, 0);
  issueK(1, 1);
  loadVI(0);
  VM_WAIT10;  // drain K(0); leave K(1)+V(0)+idn(0)=10

#pragma unroll 2
  for (int t = 0; t < 14; t++) {
    body(t & 1);           // uses K(t), vf(t), idnp(t)
    loadVI(t + 1);         // 6 reg loads
    LGKM_WAIT0;            // K(t) ds_reads definitely done before overwrite
    issueK(t + 2, t & 1);  // 4 gloads into the buf just consumed
    VM_WAIT10;             // drain K(t+1); leave V/idn(t+1)+K(t+2)=10
  }
  body(0);      // t=14
  loadVI(15);
  VM_WAIT6;     // drain K(15); leave V/idn(15)=6
  body(1);      // t=15

#pragma unroll
  for (int mi = 0; mi < 2; mi++)
#pragma unroll
    for (int nd = 0; nd < 4; nd++)
#pragma unroll
      for (int r = 0; r < 4; r++)
        atomicAdd(&Cp[(size_t)(iw + mi * 16 + qd * 4 + r) * DIM + h * DK + nd * 16 + l16],
                  acc[mi][nd][r]);
}

// ---------------------------------------------------------------- launcher
extern "C" void kernel_launch(void* const* d_in, const int* in_sizes, int n_in,
                              void* d_out, int out_size, void* d_ws, size_t ws_size,
                              hipStream_t stream) {
  const float* q  = (const float*)d_in[0];
  const float* k  = (const float*)d_in[1];
  const float* v  = (const float*)d_in[2];
  const float* Wq = (const float*)d_in[3];
  const float* bq = (const float*)d_in[4];
  const float* Wk = (const float*)d_in[5];
  const float* bk = (const float*)d_in[6];
  const float* Wv = (const float*)d_in[7];
  const float* bv = (const float*)d_in[8];
  const float* Wo = (const float*)d_in[9];
  const float* bo = (const float*)d_in[10];
  float* out = (float*)d_out;

  f16* w = (f16*)d_ws;
  f16* qh  = w;                          // 0..4MB
  f16* kh  = qh + (size_t)S_LEN * DIM;   // 4..8
  f16* vh  = kh + (size_t)S_LEN * DIM;   // 8..12
  f16* wqh = vh + (size_t)S_LEN * DIM;   // 12..14
  f16* wkh = wqh + (size_t)DIM * DIM;    // 14..16
  f16* wvh = wkh + (size_t)DIM * DIM;    // 16..18
  f16* woh = wvh + (size_t)DIM * DIM;    // 18..20
  f16* Qp  = woh + (size_t)DIM * DIM;    // 20..24
  f16* Kp  = Qp + (size_t)S_LEN * DIM;   // 24..28
  f16* Vt  = Kp + (size_t)S_LEN * DIM;   // 28..32
  f16* IDn = qh;                         // 0..8MB  [qh/kh dead after gemm_qkv]
  float* Cp = (float*)vh;                // 8..16MB [vh/wqh/wkh dead]
  f16* Ct  = qh;                         // 0..4MB  [IDn dead after attn_ctx]

  dim3 b256(256);
  cvt_all<<<dim3(1024, 10), b256, 0, stream>>>(q, k, v, Wq, Wk, Wv, Wo,
                                               qh, kh, vh, wqh, wkh, wvh, woh);

  gemm_qkv<<<dim3(DIM / 64, S_LEN / 128, 3), b256, 0, stream>>>(
      qh, kh, vh, wqh, wkh, wvh, bq, bk, bv, Qp, Kp, Vt);

  hipMemsetAsync(Cp, 0, (size_t)S_LEN * DIM * sizeof(float), stream);
  hipMemsetAsync(out, 0, (size_t)S_LEN * DIM * sizeof(float), stream);

  attn_denom<<<dim3(S_LEN / 64, S_LEN / 64), b256, 0, stream>>>(Qp, Kp, IDn);
  attn_ctx<<<dim3(S_LEN / 128, NH, 4), b256, 0, stream>>>(Qp, Kp, Vt, IDn, Cp);

  const int nqkv4 = S_LEN * DIM / 4;
  cvt_f32_f16<<<nqkv4 / 256, b256, 0, stream>>>(Cp, Ct, nqkv4);

  gemm_out<<<dim3(DIM / 64, S_LEN / 128, 2), b256, 0, stream>>>(Ct, woh, bo, out);
}

// Round 7
// 232.168 us; speedup vs baseline: 1.0745x; 1.0745x over previous
//
#include <hip/hip_runtime.h>
#include <hip/hip_fp16.h>

// MHA with softmax over HEADS axis. R14: max-TLP attn_ctx. Arc evidence:
// time tracks resident waves (R9/R12 @16 waves/CU = 52-56us; R10 @12 = 72;
// barrier-free R13 = 71) -> raise the never-turned knob: waves/CU. mi=1
// (16 i-rows/wave, 64/block) doubles grid to 2048 blocks = 8 blocks/CU =
// 32 waves/CU (HW max). Verified pieces kept: register-P swapped QK^T (R12),
// permuted-IDn f16x8 (R13), permuted Vt (R10), XCD remap (R12), R7 dbuf
// loop skeleton. LDS 16.4KB (dbuf K+V), launch_bounds(256,8), no setprio.

typedef _Float16 f16;
typedef _Float16 f16x4 __attribute__((ext_vector_type(4)));
typedef _Float16 f16x8 __attribute__((ext_vector_type(8)));
typedef float    f32x4 __attribute__((ext_vector_type(4)));

#define S_LEN 2048
#define DIM   1024
#define NH    16
#define DK    64
// exp(s * 0.125) = exp2(s * log2(e)/8)
#define EXP2K 0.1803368801111244f

#define MFMA(a, b, c) __builtin_amdgcn_mfma_f32_16x16x32_f16(a, b, c, 0, 0, 0)

#define VM_WAIT0   asm volatile("s_waitcnt vmcnt(0)" ::: "memory")
#define WG_BARRIER asm volatile("s_barrier" ::: "memory")

typedef __attribute__((address_space(1))) void g_void;
typedef __attribute__((address_space(3))) void l_void;

static __device__ __forceinline__ void gload_lds16(const void* g, void* l) {
  __builtin_amdgcn_global_load_lds((g_void*)g, (l_void*)l, 16, 0, 0);
}

static __device__ __forceinline__ float exp_s(float s) {
  return __builtin_amdgcn_exp2f(s * EXP2K);  // identical in denom & ctx
}

// ---------------------------------------------------------------- merged cvt fp32->f16
__global__ __launch_bounds__(256) void cvt_all(
    const float* __restrict__ q, const float* __restrict__ k, const float* __restrict__ v,
    const float* __restrict__ Wq, const float* __restrict__ Wk, const float* __restrict__ Wv,
    const float* __restrict__ Wo, f16* __restrict__ qh, f16* __restrict__ kh,
    f16* __restrict__ vh, f16* __restrict__ wqh, f16* __restrict__ wkh,
    f16* __restrict__ wvh, f16* __restrict__ woh) {
  const size_t M = 1048576;
  const int seg = blockIdx.y;
  const float* src;
  f16* dst;
  switch (seg) {
    case 0: src = q;      dst = qh;      break;
    case 1: src = q + M;  dst = qh + M;  break;
    case 2: src = k;      dst = kh;      break;
    case 3: src = k + M;  dst = kh + M;  break;
    case 4: src = v;      dst = vh;      break;
    case 5: src = v + M;  dst = vh + M;  break;
    case 6: src = Wq;     dst = wqh;     break;
    case 7: src = Wk;     dst = wkh;     break;
    case 8: src = Wv;     dst = wvh;     break;
    default: src = Wo;    dst = woh;     break;
  }
  int i = blockIdx.x * 256 + threadIdx.x;
  float4 vv = ((const float4*)src)[i];
  f16x4 o = {(f16)vv.x, (f16)vv.y, (f16)vv.z, (f16)vv.w};
  ((f16x4*)dst)[i] = o;
}

__global__ __launch_bounds__(256) void cvt_f32_f16(const float* __restrict__ src,
                                                   f16* __restrict__ dst, int n4) {
  int i = blockIdx.x * 256 + threadIdx.x;
  if (i < n4) {
    float4 v = ((const float4*)src)[i];
    f16x4 o = {(f16)v.x, (f16)v.y, (f16)v.z, (f16)v.w};
    ((f16x4*)dst)[i] = o;
  }
}

// ---------------------------------------------------------------- pipelined 128x64 GEMM core
static __device__ __forceinline__ void gemm32_core(const f16* __restrict__ X,
                                                   const f16* __restrict__ W,
                                                   int k0, int k1, int bm, int bn,
                                                   f16* As, f16* Bs,
                                                   f32x4 (&acc)[4][2]) {
  const int tid = threadIdx.x;
  const int wv = tid >> 6;
  const int lane = tid & 63;
  const int qd = lane >> 4;
  const int l16 = lane & 15;
  const int wm = (wv & 1) * 64;
  const int wn = (wv >> 1) * 32;
  const int lr4 = lane >> 2, lc4 = lane & 3;

  const f16* gA = X + (size_t)(bm + wv * 32 + lr4) * DIM + k0 + lc4 * 8;
  const f16* gB = W + (size_t)(bn + wv * 16 + lr4) * DIM + k0 + lc4 * 8;
  const int np = (k1 - k0) >> 5;

  // prologue: period 0 into buf 0
  gload_lds16(gA, As + (wv * 32) * 32);
  gload_lds16(gA + 16 * DIM, As + (wv * 32 + 16) * 32);
  gload_lds16(gB, Bs + (wv * 16) * 32);

#pragma unroll 2
  for (int t = 0; t < np; t++) {
    const int buf = t & 1;
    VM_WAIT0;
    WG_BARRIER;
    if (t + 1 < np) {
      const f16* gA1 = gA + (t + 1) * 32;
      const f16* gB1 = gB + (t + 1) * 32;
      f16* dA = As + (buf ^ 1) * (128 * 32);
      f16* dB = Bs + (buf ^ 1) * (64 * 32);
      gload_lds16(gA1, dA + (wv * 32) * 32);
      gload_lds16(gA1 + 16 * DIM, dA + (wv * 32 + 16) * 32);
      gload_lds16(gB1, dB + (wv * 16) * 32);
    }
    const f16* A = As + buf * (128 * 32);
    const f16* B = Bs + buf * (64 * 32);
    f16x8 bf[2];
#pragma unroll
    for (int ni = 0; ni < 2; ni++)
      bf[ni] = *(const f16x8*)&B[(wn + ni * 16 + l16) * 32 + qd * 8];
#pragma unroll
    for (int mi = 0; mi < 4; mi++) {
      f16x8 af = *(const f16x8*)&A[(wm + mi * 16 + l16) * 32 + qd * 8];
#pragma unroll
      for (int ni = 0; ni < 2; ni++)
        acc[mi][ni] = MFMA(af, bf[ni], acc[mi][ni]);
    }
  }
}

// ---------------------------------------------------------------- merged QKV proj
__global__ __launch_bounds__(256) void gemm_qkv(
    const f16* __restrict__ X0, const f16* __restrict__ X1, const f16* __restrict__ X2,
    const f16* __restrict__ W0, const f16* __restrict__ W1, const f16* __restrict__ W2,
    const float* __restrict__ b0, const float* __restrict__ b1, const float* __restrict__ b2,
    f16* __restrict__ o0, f16* __restrict__ o1, f16* __restrict__ o2) {
  __shared__ __align__(16) f16 As[2 * 128 * 32];
  __shared__ __align__(16) f16 Bs[2 * 64 * 32];
  const int z = blockIdx.z;
  const f16* X = z == 0 ? X0 : z == 1 ? X1 : X2;
  const f16* W = z == 0 ? W0 : z == 1 ? W1 : W2;
  const float* bias = z == 0 ? b0 : z == 1 ? b1 : b2;
  f16* outh = z == 0 ? o0 : z == 1 ? o1 : o2;

  const int bm = blockIdx.y * 128, bn = blockIdx.x * 64;
  f32x4 acc[4][2];
#pragma unroll
  for (int a = 0; a < 4; a++)
#pragma unroll
    for (int b = 0; b < 2; b++) acc[a][b] = (f32x4){0.f, 0.f, 0.f, 0.f};

  gemm32_core(X, W, 0, DIM, bm, bn, As, Bs, acc);

  const int tid = threadIdx.x;
  const int wv = tid >> 6, lane = tid & 63;
  const int qd = lane >> 4, l16 = lane & 15;
  const int wm = (wv & 1) * 64, wn = (wv >> 1) * 32;
#pragma unroll
  for (int mi = 0; mi < 4; mi++) {
#pragma unroll
    for (int ni = 0; ni < 2; ni++) {
      const int gm = bm + wm + mi * 16 + qd * 4;
      const int gn = bn + wn + ni * 16 + l16;
      const float bs = bias[gn];
      if (z == 2) {
        f16x4 o = {(f16)(acc[mi][ni][0] + bs), (f16)(acc[mi][ni][1] + bs),
                   (f16)(acc[mi][ni][2] + bs), (f16)(acc[mi][ni][3] + bs)};
        // Vt stored j-PERMUTED within each 32-block: storage[pi(j)] = V[j],
        // pi(gm) = (gm&~31) + ((gm>>2)&3)*8 + ((gm>>4)&1)*4 + (gm&3).
        const int pj = (gm & ~31) + ((gm >> 2) & 3) * 8 + ((gm >> 4) & 1) * 4;
        *(f16x4*)&outh[(size_t)gn * S_LEN + pj] = o;  // Vt[d][perm j]
      } else {
#pragma unroll
        for (int r = 0; r < 4; r++)
          outh[(size_t)(gm + r) * DIM + gn] = (f16)(acc[mi][ni][r] + bs);
      }
    }
  }
}

// ---------------------------------------------------------------- out GEMM 128x64, splitK2
__global__ __launch_bounds__(256) void gemm_out(const f16* __restrict__ X,
                                                const f16* __restrict__ W,
                                                const float* __restrict__ bias,
                                                float* __restrict__ outf) {
  __shared__ __align__(16) f16 As[2 * 128 * 32];
  __shared__ __align__(16) f16 Bs[2 * 64 * 32];
  const int z = blockIdx.z;
  const int bm = blockIdx.y * 128, bn = blockIdx.x * 64;
  f32x4 acc[4][2];
#pragma unroll
  for (int a = 0; a < 4; a++)
#pragma unroll
    for (int b = 0; b < 2; b++) acc[a][b] = (f32x4){0.f, 0.f, 0.f, 0.f};

  gemm32_core(X, W, z * (DIM / 2), (z + 1) * (DIM / 2), bm, bn, As, Bs, acc);

  const int tid = threadIdx.x;
  const int wv = tid >> 6, lane = tid & 63;
  const int qd = lane >> 4, l16 = lane & 15;
  const int wm = (wv & 1) * 64, wn = (wv >> 1) * 32;
#pragma unroll
  for (int mi = 0; mi < 4; mi++) {
#pragma unroll
    for (int ni = 0; ni < 2; ni++) {
      const int gm = bm + wm + mi * 16 + qd * 4;
      const int gn = bn + wn + ni * 16 + l16;
      const float bs = z == 0 ? bias[gn] : 0.f;
#pragma unroll
      for (int r = 0; r < 4; r++)
        atomicAdd(&outf[(size_t)(gm + r) * DIM + gn], acc[mi][ni][r] + bs);
    }
  }
}

// ---------------------------------------------------------------- pass A: IDn = 1/sum_h exp
// 64x64 tile, grid 1024. IDn stored j-PERMUTED (same pi as Vt) so attn_ctx
// reads one f16x8 covering both ni sub-tiles, elementwise-aligned with P.
__global__ __launch_bounds__(256) void attn_denom(const f16* __restrict__ Qp,
                                                  const f16* __restrict__ Kp,
                                                  f16* __restrict__ IDn) {
  __shared__ __align__(16) f16 Qs[2][2][64 * 32];  // [buf][kk][row][32]
  __shared__ __align__(16) f16 Ks[2][2][64 * 32];
  const int tid = threadIdx.x;
  const int wv = tid >> 6;
  const int lane = tid & 63;
  const int qd = lane >> 4;
  const int l16 = lane & 15;
  const int wm = (wv & 1) * 32, wn = (wv >> 1) * 32;
  const int bi = blockIdx.y * 64, bj = blockIdx.x * 64;
  const int lr4 = lane >> 2, lc4 = lane & 3;
  const int kkw = wv & 1;
  const int q0 = (wv >> 1) * 2;

  f32x4 dsum[2][2];
#pragma unroll
  for (int a = 0; a < 2; a++)
#pragma unroll
    for (int b = 0; b < 2; b++) dsum[a][b] = (f32x4){0.f, 0.f, 0.f, 0.f};

  // prologue: head 0 -> buf 0
  {
    const f16* gq = Qp + (size_t)(bi + q0 * 16 + lr4) * DIM + kkw * 32 + lc4 * 8;
    const f16* gk = Kp + (size_t)(bj + q0 * 16 + lr4) * DIM + kkw * 32 + lc4 * 8;
#pragma unroll
    for (int t = 0; t < 2; t++) {
      gload_lds16(gq + (size_t)t * 16 * DIM, &Qs[0][kkw][(q0 + t) * 16 * 32]);
      gload_lds16(gk + (size_t)t * 16 * DIM, &Ks[0][kkw][(q0 + t) * 16 * 32]);
    }
  }

#pragma unroll 2
  for (int h = 0; h < NH; h++) {
    const int buf = h & 1;
    VM_WAIT0;
    WG_BARRIER;
    if (h + 1 < NH) {
      const f16* gq = Qp + (size_t)(bi + q0 * 16 + lr4) * DIM + (h + 1) * DK + kkw * 32 + lc4 * 8;
      const f16* gk = Kp + (size_t)(bj + q0 * 16 + lr4) * DIM + (h + 1) * DK + kkw * 32 + lc4 * 8;
#pragma unroll
      for (int t = 0; t < 2; t++) {
        gload_lds16(gq + (size_t)t * 16 * DIM, &Qs[buf ^ 1][kkw][(q0 + t) * 16 * 32]);
        gload_lds16(gk + (size_t)t * 16 * DIM, &Ks[buf ^ 1][kkw][(q0 + t) * 16 * 32]);
      }
    }

#pragma unroll
    for (int mi = 0; mi < 2; mi++) {
      f16x8 af0 = *(const f16x8*)&Qs[buf][0][(wm + mi * 16 + l16) * 32 + qd * 8];
      f16x8 af1 = *(const f16x8*)&Qs[buf][1][(wm + mi * 16 + l16) * 32 + qd * 8];
#pragma unroll
      for (int ni = 0; ni < 2; ni++) {
        f16x8 bf0 = *(const f16x8*)&Ks[buf][0][(wn + ni * 16 + l16) * 32 + qd * 8];
        f16x8 bf1 = *(const f16x8*)&Ks[buf][1][(wn + ni * 16 + l16) * 32 + qd * 8];
        f32x4 s = {0.f, 0.f, 0.f, 0.f};
        s = MFMA(af0, bf0, s);  // kk order identical to attn_ctx
        s = MFMA(af1, bf1, s);
#pragma unroll
        for (int r = 0; r < 4; r++) dsum[mi][ni][r] += exp_s(s[r]);
      }
    }
  }
#pragma unroll
  for (int mi = 0; mi < 2; mi++)
#pragma unroll
    for (int ni = 0; ni < 2; ni++)
#pragma unroll
      for (int r = 0; r < 4; r++) {
        const int gi = bi + wm + mi * 16 + qd * 4 + r;
        const int gj = bj + wn + ni * 16 + l16;
        // j-permuted store (same pi as Vt): IDnP[pi(gj)] = 1/dsum(gj)
        const int pj = (gj & ~31) + ((gj >> 2) & 3) * 8 + ((gj >> 4) & 1) * 4 + (gj & 3);
        IDn[(size_t)gi * S_LEN + pj] = (f16)(1.f / dsum[mi][ni][r]);
      }
}

// ---------------------------------------------------------------- pass B: ctx
// grid (32, 16, 4) = 2048 blocks = 8 blocks/CU = 32 waves/CU (HW max).
// Each wave owns 16 i-rows (mi=1). Register-P swapped QK^T; permuted-IDn
// f16x8; dbuf K/V LDS (16KB), R7 skeleton (wait0+barrier+issue+compute).
__global__ __launch_bounds__(256, 8) void attn_ctx(const f16* __restrict__ Qp,
                                                   const f16* __restrict__ Kp,
                                                   const f16* __restrict__ Vt,
                                                   const f16* __restrict__ IDn,
                                                   float* __restrict__ Cp) {
  __shared__ __align__(16) f16 Ks[2][2][32 * 32];  // [buf][kk][j32][dk32] 8KB
  __shared__ __align__(16) f16 Vs[2][64 * 32];     // [buf][d64][j32 perm]  8KB
  const int tid = threadIdx.x;
  const int wv = tid >> 6;
  const int lane = tid & 63;
  const int qd = lane >> 4;
  const int l16 = lane & 15;
  // XCD-aware remap over flat 2048: 256-block chunks/XCD (same h/z group
  // shares K/V/IDn slices; ~3MB working set fits 4MB L2).
  const int flat = blockIdx.x + (blockIdx.y << 5) + (blockIdx.z << 9);
  const int nf = ((flat & 7) << 8) + (flat >> 3);
  const int h = (nf >> 5) & 15;
  const int iw = (nf & 31) * 64 + wv * 16;
  const int jb = (nf >> 9) * 512;
  const int lr4 = lane >> 2, lc4 = lane & 3;
  const int kkw = wv & 1;
  const int rhw = wv >> 1;

  // Q fragment (B-operand of swapped QK^T), 1 mi
  f16x8 aq[2];
#pragma unroll
  for (int kk = 0; kk < 2; kk++)
    aq[kk] = *(const f16x8*)(Qp + (size_t)(iw + l16) * DIM + h * DK + kk * 32 + qd * 8);

  f32x4 acc[4];
#pragma unroll
  for (int b = 0; b < 4; b++) acc[b] = (f32x4){0.f, 0.f, 0.f, 0.f};

  f16x8 idn[2];  // [buf] permuted-IDn, elementwise aligned with P

  // one group = 3 vmem ops/wave: K gload + V gload + idn f16x8
  auto issue = [&](int tt, int pb) {
    const int j1 = jb + tt * 32;
    gload_lds16(Kp + (size_t)(j1 + rhw * 16 + lr4) * DIM + h * DK + kkw * 32 + lc4 * 8,
                &Ks[pb][kkw][(rhw * 16) * 32]);
    gload_lds16(Vt + (size_t)(h * DK + wv * 16 + lr4) * S_LEN + j1 + lc4 * 8,
                &Vs[pb][(wv * 16) * 32]);
    idn[pb] = *(const f16x8*)(IDn + (size_t)(iw + l16) * S_LEN + j1 + qd * 8);
  };

  issue(0, 0);

#pragma unroll 2
  for (int t = 0; t < 16; t++) {
    const int buf = t & 1;
    VM_WAIT0;
    WG_BARRIER;
    if (t + 1 < 16) issue(t + 1, buf ^ 1);

    // K fragments (A-operand: row=j, k=dk)
    f16x8 bk[2][2];
#pragma unroll
    for (int ni = 0; ni < 2; ni++)
#pragma unroll
      for (int kk = 0; kk < 2; kk++)
        bk[ni][kk] = *(const f16x8*)&Ks[buf][kk][(ni * 16 + l16) * 32 + qd * 8];

    // swapped QK^T + exp + permuted-IDn scale, all lane-local
    f32x4 st0 = {0.f, 0.f, 0.f, 0.f};
    f32x4 st1 = {0.f, 0.f, 0.f, 0.f};
    st0 = MFMA(bk[0][0], aq[0], st0);  // kk order identical to attn_denom
    st0 = MFMA(bk[0][1], aq[1], st0);
    st1 = MFMA(bk[1][0], aq[0], st1);
    st1 = MFMA(bk[1][1], aq[1], st1);
    f16x8 p;
#pragma unroll
    for (int r = 0; r < 4; r++) p[r] = (f16)(exp_s(st0[r]) * (float)idn[buf][r]);
#pragma unroll
    for (int r = 0; r < 4; r++) p[4 + r] = (f16)(exp_s(st1[r]) * (float)idn[buf][4 + r]);

    // PV: B-operand b128 from permuted Vs (k-slot matches P layout)
    f16x8 bv[4];
#pragma unroll
    for (int nd = 0; nd < 4; nd++)
      bv[nd] = *(const f16x8*)&Vs[buf][(nd * 16 + l16) * 32 + qd * 8];
#pragma unroll
    for (int nd = 0; nd < 4; nd++)
      acc[nd] = MFMA(p, bv[nd], acc[nd]);
  }

#pragma unroll
  for (int nd = 0; nd < 4; nd++)
#pragma unroll
    for (int r = 0; r < 4; r++)
      atomicAdd(&Cp[(size_t)(iw + qd * 4 + r) * DIM + h * DK + nd * 16 + l16],
                acc[nd][r]);
}

// ---------------------------------------------------------------- launcher
extern "C" void kernel_launch(void* const* d_in, const int* in_sizes, int n_in,
                              void* d_out, int out_size, void* d_ws, size_t ws_size,
                              hipStream_t stream) {
  const float* q  = (const float*)d_in[0];
  const float* k  = (const float*)d_in[1];
  const float* v  = (const float*)d_in[2];
  const float* Wq = (const float*)d_in[3];
  const float* bq = (const float*)d_in[4];
  const float* Wk = (const float*)d_in[5];
  const float* bk = (const float*)d_in[6];
  const float* Wv = (const float*)d_in[7];
  const float* bv = (const float*)d_in[8];
  const float* Wo = (const float*)d_in[9];
  const float* bo = (const float*)d_in[10];
  float* out = (float*)d_out;

  f16* w = (f16*)d_ws;
  f16* qh  = w;                          // 0..4MB
  f16* kh  = qh + (size_t)S_LEN * DIM;   // 4..8
  f16* vh  = kh + (size_t)S_LEN * DIM;   // 8..12
  f16* wqh = vh + (size_t)S_LEN * DIM;   // 12..14
  f16* wkh = wqh + (size_t)DIM * DIM;    // 14..16
  f16* wvh = wkh + (size_t)DIM * DIM;    // 16..18
  f16* woh = wvh + (size_t)DIM * DIM;    // 18..20
  f16* Qp  = woh + (size_t)DIM * DIM;    // 20..24
  f16* Kp  = Qp + (size_t)S_LEN * DIM;   // 24..28
  f16* Vt  = Kp + (size_t)S_LEN * DIM;   // 28..32
  f16* IDn = qh;                         // 0..8MB  [qh/kh dead after gemm_qkv]
  float* Cp = (float*)vh;                // 8..16MB [vh/wqh/wkh dead]
  f16* Ct  = qh;                         // 0..4MB  [IDn dead after attn_ctx]

  dim3 b256(256);
  cvt_all<<<dim3(1024, 10), b256, 0, stream>>>(q, k, v, Wq, Wk, Wv, Wo,
                                               qh, kh, vh, wqh, wkh, wvh, woh);

  gemm_qkv<<<dim3(DIM / 64, S_LEN / 128, 3), b256, 0, stream>>>(
      qh, kh, vh, wqh, wkh, wvh, bq, bk, bv, Qp, Kp, Vt);

  hipMemsetAsync(Cp, 0, (size_t)S_LEN * DIM * sizeof(float), stream);
  hipMemsetAsync(out, 0, (size_t)S_LEN * DIM * sizeof(float), stream);

  attn_denom<<<dim3(S_LEN / 64, S_LEN / 64), b256, 0, stream>>>(Qp, Kp, IDn);
  attn_ctx<<<dim3(S_LEN / 64, NH, 4), b256, 0, stream>>>(Qp, Kp, Vt, IDn, Cp);

  const int nqkv4 = S_LEN * DIM / 4;
  cvt_f32_f16<<<nqkv4 / 256, b256, 0, stream>>>(Cp, Ct, nqkv4);

  gemm_out<<<dim3(DIM / 64, S_LEN / 128, 2), b256, 0, stream>>>(Ct, woh, bo, out);
}

// Round 8
// 213.710 us; speedup vs baseline: 1.1673x; 1.0864x over previous
//
#include <hip/hip_runtime.h>
#include <hip/hip_fp16.h>

// MHA with softmax over HEADS axis. R15: consolidation. R14 falsified the
// occupancy theory (32 waves/CU vs 16: dur unchanged) -> the ~52us wall is
// the per-iteration work itself, not scheduling. This round reduces WORK:
// attn_ctx keeps R14's verified loop body but z=2 with direct f16 stores to
// two disjoint half-buffers (no Cp f32 atomics, no Cp memset), and a tiny
// f16 sum kernel replaces cvt_f32_f16 (12MB vs 20MB + f32 round-trip).

typedef _Float16 f16;
typedef _Float16 f16x4 __attribute__((ext_vector_type(4)));
typedef _Float16 f16x8 __attribute__((ext_vector_type(8)));
typedef float    f32x4 __attribute__((ext_vector_type(4)));

#define S_LEN 2048
#define DIM   1024
#define NH    16
#define DK    64
// exp(s * 0.125) = exp2(s * log2(e)/8)
#define EXP2K 0.1803368801111244f

#define MFMA(a, b, c) __builtin_amdgcn_mfma_f32_16x16x32_f16(a, b, c, 0, 0, 0)

#define VM_WAIT0   asm volatile("s_waitcnt vmcnt(0)" ::: "memory")
#define WG_BARRIER asm volatile("s_barrier" ::: "memory")

typedef __attribute__((address_space(1))) void g_void;
typedef __attribute__((address_space(3))) void l_void;

static __device__ __forceinline__ void gload_lds16(const void* g, void* l) {
  __builtin_amdgcn_global_load_lds((g_void*)g, (l_void*)l, 16, 0, 0);
}

static __device__ __forceinline__ float exp_s(float s) {
  return __builtin_amdgcn_exp2f(s * EXP2K);  // identical in denom & ctx
}

// ---------------------------------------------------------------- merged cvt fp32->f16
__global__ __launch_bounds__(256) void cvt_all(
    const float* __restrict__ q, const float* __restrict__ k, const float* __restrict__ v,
    const float* __restrict__ Wq, const float* __restrict__ Wk, const float* __restrict__ Wv,
    const float* __restrict__ Wo, f16* __restrict__ qh, f16* __restrict__ kh,
    f16* __restrict__ vh, f16* __restrict__ wqh, f16* __restrict__ wkh,
    f16* __restrict__ wvh, f16* __restrict__ woh) {
  const size_t M = 1048576;
  const int seg = blockIdx.y;
  const float* src;
  f16* dst;
  switch (seg) {
    case 0: src = q;      dst = qh;      break;
    case 1: src = q + M;  dst = qh + M;  break;
    case 2: src = k;      dst = kh;      break;
    case 3: src = k + M;  dst = kh + M;  break;
    case 4: src = v;      dst = vh;      break;
    case 5: src = v + M;  dst = vh + M;  break;
    case 6: src = Wq;     dst = wqh;     break;
    case 7: src = Wk;     dst = wkh;     break;
    case 8: src = Wv;     dst = wvh;     break;
    default: src = Wo;    dst = woh;     break;
  }
  int i = blockIdx.x * 256 + threadIdx.x;
  float4 vv = ((const float4*)src)[i];
  f16x4 o = {(f16)vv.x, (f16)vv.y, (f16)vv.z, (f16)vv.w};
  ((f16x4*)dst)[i] = o;
}

// ---------------------------------------------------------------- Ct = C0 + C1 (f16, f32 math)
__global__ __launch_bounds__(256) void sum_halves(const f16* __restrict__ a,
                                                  const f16* __restrict__ b,
                                                  f16* __restrict__ o) {
  int i = blockIdx.x * 256 + threadIdx.x;
  f16x8 x = ((const f16x8*)a)[i];
  f16x8 y = ((const f16x8*)b)[i];
  f16x8 r;
#pragma unroll
  for (int j = 0; j < 8; j++) r[j] = (f16)((float)x[j] + (float)y[j]);
  ((f16x8*)o)[i] = r;
}

// ---------------------------------------------------------------- pipelined 128x64 GEMM core
static __device__ __forceinline__ void gemm32_core(const f16* __restrict__ X,
                                                   const f16* __restrict__ W,
                                                   int k0, int k1, int bm, int bn,
                                                   f16* As, f16* Bs,
                                                   f32x4 (&acc)[4][2]) {
  const int tid = threadIdx.x;
  const int wv = tid >> 6;
  const int lane = tid & 63;
  const int qd = lane >> 4;
  const int l16 = lane & 15;
  const int wm = (wv & 1) * 64;
  const int wn = (wv >> 1) * 32;
  const int lr4 = lane >> 2, lc4 = lane & 3;

  const f16* gA = X + (size_t)(bm + wv * 32 + lr4) * DIM + k0 + lc4 * 8;
  const f16* gB = W + (size_t)(bn + wv * 16 + lr4) * DIM + k0 + lc4 * 8;
  const int np = (k1 - k0) >> 5;

  // prologue: period 0 into buf 0
  gload_lds16(gA, As + (wv * 32) * 32);
  gload_lds16(gA + 16 * DIM, As + (wv * 32 + 16) * 32);
  gload_lds16(gB, Bs + (wv * 16) * 32);

#pragma unroll 2
  for (int t = 0; t < np; t++) {
    const int buf = t & 1;
    VM_WAIT0;
    WG_BARRIER;
    if (t + 1 < np) {
      const f16* gA1 = gA + (t + 1) * 32;
      const f16* gB1 = gB + (t + 1) * 32;
      f16* dA = As + (buf ^ 1) * (128 * 32);
      f16* dB = Bs + (buf ^ 1) * (64 * 32);
      gload_lds16(gA1, dA + (wv * 32) * 32);
      gload_lds16(gA1 + 16 * DIM, dA + (wv * 32 + 16) * 32);
      gload_lds16(gB1, dB + (wv * 16) * 32);
    }
    const f16* A = As + buf * (128 * 32);
    const f16* B = Bs + buf * (64 * 32);
    f16x8 bf[2];
#pragma unroll
    for (int ni = 0; ni < 2; ni++)
      bf[ni] = *(const f16x8*)&B[(wn + ni * 16 + l16) * 32 + qd * 8];
#pragma unroll
    for (int mi = 0; mi < 4; mi++) {
      f16x8 af = *(const f16x8*)&A[(wm + mi * 16 + l16) * 32 + qd * 8];
#pragma unroll
      for (int ni = 0; ni < 2; ni++)
        acc[mi][ni] = MFMA(af, bf[ni], acc[mi][ni]);
    }
  }
}

// ---------------------------------------------------------------- merged QKV proj
__global__ __launch_bounds__(256) void gemm_qkv(
    const f16* __restrict__ X0, const f16* __restrict__ X1, const f16* __restrict__ X2,
    const f16* __restrict__ W0, const f16* __restrict__ W1, const f16* __restrict__ W2,
    const float* __restrict__ b0, const float* __restrict__ b1, const float* __restrict__ b2,
    f16* __restrict__ o0, f16* __restrict__ o1, f16* __restrict__ o2) {
  __shared__ __align__(16) f16 As[2 * 128 * 32];
  __shared__ __align__(16) f16 Bs[2 * 64 * 32];
  const int z = blockIdx.z;
  const f16* X = z == 0 ? X0 : z == 1 ? X1 : X2;
  const f16* W = z == 0 ? W0 : z == 1 ? W1 : W2;
  const float* bias = z == 0 ? b0 : z == 1 ? b1 : b2;
  f16* outh = z == 0 ? o0 : z == 1 ? o1 : o2;

  const int bm = blockIdx.y * 128, bn = blockIdx.x * 64;
  f32x4 acc[4][2];
#pragma unroll
  for (int a = 0; a < 4; a++)
#pragma unroll
    for (int b = 0; b < 2; b++) acc[a][b] = (f32x4){0.f, 0.f, 0.f, 0.f};

  gemm32_core(X, W, 0, DIM, bm, bn, As, Bs, acc);

  const int tid = threadIdx.x;
  const int wv = tid >> 6, lane = tid & 63;
  const int qd = lane >> 4, l16 = lane & 15;
  const int wm = (wv & 1) * 64, wn = (wv >> 1) * 32;
#pragma unroll
  for (int mi = 0; mi < 4; mi++) {
#pragma unroll
    for (int ni = 0; ni < 2; ni++) {
      const int gm = bm + wm + mi * 16 + qd * 4;
      const int gn = bn + wn + ni * 16 + l16;
      const float bs = bias[gn];
      if (z == 2) {
        f16x4 o = {(f16)(acc[mi][ni][0] + bs), (f16)(acc[mi][ni][1] + bs),
                   (f16)(acc[mi][ni][2] + bs), (f16)(acc[mi][ni][3] + bs)};
        // Vt stored j-PERMUTED within each 32-block: storage[pi(j)] = V[j],
        // pi(gm) = (gm&~31) + ((gm>>2)&3)*8 + ((gm>>4)&1)*4 + (gm&3).
        const int pj = (gm & ~31) + ((gm >> 2) & 3) * 8 + ((gm >> 4) & 1) * 4;
        *(f16x4*)&outh[(size_t)gn * S_LEN + pj] = o;  // Vt[d][perm j]
      } else {
#pragma unroll
        for (int r = 0; r < 4; r++)
          outh[(size_t)(gm + r) * DIM + gn] = (f16)(acc[mi][ni][r] + bs);
      }
    }
  }
}

// ---------------------------------------------------------------- out GEMM 128x64, splitK2
__global__ __launch_bounds__(256) void gemm_out(const f16* __restrict__ X,
                                                const f16* __restrict__ W,
                                                const float* __restrict__ bias,
                                                float* __restrict__ outf) {
  __shared__ __align__(16) f16 As[2 * 128 * 32];
  __shared__ __align__(16) f16 Bs[2 * 64 * 32];
  const int z = blockIdx.z;
  const int bm = blockIdx.y * 128, bn = blockIdx.x * 64;
  f32x4 acc[4][2];
#pragma unroll
  for (int a = 0; a < 4; a++)
#pragma unroll
    for (int b = 0; b < 2; b++) acc[a][b] = (f32x4){0.f, 0.f, 0.f, 0.f};

  gemm32_core(X, W, z * (DIM / 2), (z + 1) * (DIM / 2), bm, bn, As, Bs, acc);

  const int tid = threadIdx.x;
  const int wv = tid >> 6, lane = tid & 63;
  const int qd = lane >> 4, l16 = lane & 15;
  const int wm = (wv & 1) * 64, wn = (wv >> 1) * 32;
#pragma unroll
  for (int mi = 0; mi < 4; mi++) {
#pragma unroll
    for (int ni = 0; ni < 2; ni++) {
      const int gm = bm + wm + mi * 16 + qd * 4;
      const int gn = bn + wn + ni * 16 + l16;
      const float bs = z == 0 ? bias[gn] : 0.f;
#pragma unroll
      for (int r = 0; r < 4; r++)
        atomicAdd(&outf[(size_t)(gm + r) * DIM + gn], acc[mi][ni][r] + bs);
    }
  }
}

// ---------------------------------------------------------------- pass A: IDn = 1/sum_h exp
// 64x64 tile, grid 1024. IDn stored j-PERMUTED (same pi as Vt) so attn_ctx
// reads one f16x8 covering both ni sub-tiles, elementwise-aligned with P.
__global__ __launch_bounds__(256) void attn_denom(const f16* __restrict__ Qp,
                                                  const f16* __restrict__ Kp,
                                                  f16* __restrict__ IDn) {
  __shared__ __align__(16) f16 Qs[2][2][64 * 32];  // [buf][kk][row][32]
  __shared__ __align__(16) f16 Ks[2][2][64 * 32];
  const int tid = threadIdx.x;
  const int wv = tid >> 6;
  const int lane = tid & 63;
  const int qd = lane >> 4;
  const int l16 = lane & 15;
  const int wm = (wv & 1) * 32, wn = (wv >> 1) * 32;
  const int bi = blockIdx.y * 64, bj = blockIdx.x * 64;
  const int lr4 = lane >> 2, lc4 = lane & 3;
  const int kkw = wv & 1;
  const int q0 = (wv >> 1) * 2;

  f32x4 dsum[2][2];
#pragma unroll
  for (int a = 0; a < 2; a++)
#pragma unroll
    for (int b = 0; b < 2; b++) dsum[a][b] = (f32x4){0.f, 0.f, 0.f, 0.f};

  // prologue: head 0 -> buf 0
  {
    const f16* gq = Qp + (size_t)(bi + q0 * 16 + lr4) * DIM + kkw * 32 + lc4 * 8;
    const f16* gk = Kp + (size_t)(bj + q0 * 16 + lr4) * DIM + kkw * 32 + lc4 * 8;
#pragma unroll
    for (int t = 0; t < 2; t++) {
      gload_lds16(gq + (size_t)t * 16 * DIM, &Qs[0][kkw][(q0 + t) * 16 * 32]);
      gload_lds16(gk + (size_t)t * 16 * DIM, &Ks[0][kkw][(q0 + t) * 16 * 32]);
    }
  }

#pragma unroll 2
  for (int h = 0; h < NH; h++) {
    const int buf = h & 1;
    VM_WAIT0;
    WG_BARRIER;
    if (h + 1 < NH) {
      const f16* gq = Qp + (size_t)(bi + q0 * 16 + lr4) * DIM + (h + 1) * DK + kkw * 32 + lc4 * 8;
      const f16* gk = Kp + (size_t)(bj + q0 * 16 + lr4) * DIM + (h + 1) * DK + kkw * 32 + lc4 * 8;
#pragma unroll
      for (int t = 0; t < 2; t++) {
        gload_lds16(gq + (size_t)t * 16 * DIM, &Qs[buf ^ 1][kkw][(q0 + t) * 16 * 32]);
        gload_lds16(gk + (size_t)t * 16 * DIM, &Ks[buf ^ 1][kkw][(q0 + t) * 16 * 32]);
      }
    }

#pragma unroll
    for (int mi = 0; mi < 2; mi++) {
      f16x8 af0 = *(const f16x8*)&Qs[buf][0][(wm + mi * 16 + l16) * 32 + qd * 8];
      f16x8 af1 = *(const f16x8*)&Qs[buf][1][(wm + mi * 16 + l16) * 32 + qd * 8];
#pragma unroll
      for (int ni = 0; ni < 2; ni++) {
        f16x8 bf0 = *(const f16x8*)&Ks[buf][0][(wn + ni * 16 + l16) * 32 + qd * 8];
        f16x8 bf1 = *(const f16x8*)&Ks[buf][1][(wn + ni * 16 + l16) * 32 + qd * 8];
        f32x4 s = {0.f, 0.f, 0.f, 0.f};
        s = MFMA(af0, bf0, s);  // kk order identical to attn_ctx
        s = MFMA(af1, bf1, s);
#pragma unroll
        for (int r = 0; r < 4; r++) dsum[mi][ni][r] += exp_s(s[r]);
      }
    }
  }
#pragma unroll
  for (int mi = 0; mi < 2; mi++)
#pragma unroll
    for (int ni = 0; ni < 2; ni++)
#pragma unroll
      for (int r = 0; r < 4; r++) {
        const int gi = bi + wm + mi * 16 + qd * 4 + r;
        const int gj = bj + wn + ni * 16 + l16;
        // j-permuted store (same pi as Vt): IDnP[pi(gj)] = 1/dsum(gj)
        const int pj = (gj & ~31) + ((gj >> 2) & 3) * 8 + ((gj >> 4) & 1) * 4 + (gj & 3);
        IDn[(size_t)gi * S_LEN + pj] = (f16)(1.f / dsum[mi][ni][r]);
      }
}

// ---------------------------------------------------------------- pass B: ctx
// grid (32, 16, 2) = 1024 blocks = 4 blocks/CU. R14's verified loop body
// unchanged (mi=1, KVBLK=32, dbuf, wait0+barrier); z=2 with direct f16
// stores to disjoint half-buffers C0/C1 (no atomics, no Cp, no memset).
__global__ __launch_bounds__(256, 8) void attn_ctx(const f16* __restrict__ Qp,
                                                   const f16* __restrict__ Kp,
                                                   const f16* __restrict__ Vt,
                                                   const f16* __restrict__ IDn,
                                                   f16* __restrict__ C0,
                                                   f16* __restrict__ C1) {
  __shared__ __align__(16) f16 Ks[2][2][32 * 32];  // [buf][kk][j32][dk32] 8KB
  __shared__ __align__(16) f16 Vs[2][64 * 32];     // [buf][d64][j32 perm]  8KB
  const int tid = threadIdx.x;
  const int wv = tid >> 6;
  const int lane = tid & 63;
  const int qd = lane >> 4;
  const int l16 = lane & 15;
  // XCD-aware remap over flat 1024: 128-block chunks/XCD (z fixed, 4 heads,
  // all i-tiles per XCD -> K/V 1MB + IDn slice in L2).
  const int flat = blockIdx.x + (blockIdx.y << 5) + (blockIdx.z << 9);
  const int nf = ((flat & 7) << 7) + (flat >> 3);
  const int h = (nf >> 5) & 15;
  const int iw = (nf & 31) * 64 + wv * 16;
  const int z = nf >> 9;
  const int jb = z * 1024;
  f16* Cz = z == 0 ? C0 : C1;
  const int lr4 = lane >> 2, lc4 = lane & 3;
  const int kkw = wv & 1;
  const int rhw = wv >> 1;

  // Q fragment (B-operand of swapped QK^T), 1 mi
  f16x8 aq[2];
#pragma unroll
  for (int kk = 0; kk < 2; kk++)
    aq[kk] = *(const f16x8*)(Qp + (size_t)(iw + l16) * DIM + h * DK + kk * 32 + qd * 8);

  f32x4 acc[4];
#pragma unroll
  for (int b = 0; b < 4; b++) acc[b] = (f32x4){0.f, 0.f, 0.f, 0.f};

  f16x8 idn[2];  // [buf] permuted-IDn, elementwise aligned with P

  // one group = 3 vmem ops/wave: K gload + V gload + idn f16x8
  auto issue = [&](int tt, int pb) {
    const int j1 = jb + tt * 32;
    gload_lds16(Kp + (size_t)(j1 + rhw * 16 + lr4) * DIM + h * DK + kkw * 32 + lc4 * 8,
                &Ks[pb][kkw][(rhw * 16) * 32]);
    gload_lds16(Vt + (size_t)(h * DK + wv * 16 + lr4) * S_LEN + j1 + lc4 * 8,
                &Vs[pb][(wv * 16) * 32]);
    idn[pb] = *(const f16x8*)(IDn + (size_t)(iw + l16) * S_LEN + j1 + qd * 8);
  };

  issue(0, 0);

#pragma unroll 2
  for (int t = 0; t < 32; t++) {
    const int buf = t & 1;
    VM_WAIT0;
    WG_BARRIER;
    if (t + 1 < 32) issue(t + 1, buf ^ 1);

    // K fragments (A-operand: row=j, k=dk)
    f16x8 bk[2][2];
#pragma unroll
    for (int ni = 0; ni < 2; ni++)
#pragma unroll
      for (int kk = 0; kk < 2; kk++)
        bk[ni][kk] = *(const f16x8*)&Ks[buf][kk][(ni * 16 + l16) * 32 + qd * 8];

    // swapped QK^T + exp + permuted-IDn scale, all lane-local
    f32x4 st0 = {0.f, 0.f, 0.f, 0.f};
    f32x4 st1 = {0.f, 0.f, 0.f, 0.f};
    st0 = MFMA(bk[0][0], aq[0], st0);  // kk order identical to attn_denom
    st0 = MFMA(bk[0][1], aq[1], st0);
    st1 = MFMA(bk[1][0], aq[0], st1);
    st1 = MFMA(bk[1][1], aq[1], st1);
    f16x8 p;
#pragma unroll
    for (int r = 0; r < 4; r++) p[r] = (f16)(exp_s(st0[r]) * (float)idn[buf][r]);
#pragma unroll
    for (int r = 0; r < 4; r++) p[4 + r] = (f16)(exp_s(st1[r]) * (float)idn[buf][4 + r]);

    // PV: B-operand b128 from permuted Vs (k-slot matches P layout)
    f16x8 bv[4];
#pragma unroll
    for (int nd = 0; nd < 4; nd++)
      bv[nd] = *(const f16x8*)&Vs[buf][(nd * 16 + l16) * 32 + qd * 8];
#pragma unroll
    for (int nd = 0; nd < 4; nd++)
      acc[nd] = MFMA(p, bv[nd], acc[nd]);
  }

  // direct f16 store (disjoint per z) — no atomics
#pragma unroll
  for (int nd = 0; nd < 4; nd++)
#pragma unroll
    for (int r = 0; r < 4; r++)
      Cz[(size_t)(iw + qd * 4 + r) * DIM + h * DK + nd * 16 + l16] = (f16)acc[nd][r];
}

// ---------------------------------------------------------------- launcher
extern "C" void kernel_launch(void* const* d_in, const int* in_sizes, int n_in,
                              void* d_out, int out_size, void* d_ws, size_t ws_size,
                              hipStream_t stream) {
  const float* q  = (const float*)d_in[0];
  const float* k  = (const float*)d_in[1];
  const float* v  = (const float*)d_in[2];
  const float* Wq = (const float*)d_in[3];
  const float* bq = (const float*)d_in[4];
  const float* Wk = (const float*)d_in[5];
  const float* bk = (const float*)d_in[6];
  const float* Wv = (const float*)d_in[7];
  const float* bv = (const float*)d_in[8];
  const float* Wo = (const float*)d_in[9];
  const float* bo = (const float*)d_in[10];
  float* out = (float*)d_out;

  f16* w = (f16*)d_ws;
  f16* qh  = w;                          // 0..4MB
  f16* kh  = qh + (size_t)S_LEN * DIM;   // 4..8
  f16* vh  = kh + (size_t)S_LEN * DIM;   // 8..12
  f16* wqh = vh + (size_t)S_LEN * DIM;   // 12..14
  f16* wkh = wqh + (size_t)DIM * DIM;    // 14..16
  f16* wvh = wkh + (size_t)DIM * DIM;    // 16..18
  f16* woh = wvh + (size_t)DIM * DIM;    // 18..20
  f16* Qp  = woh + (size_t)DIM * DIM;    // 20..24
  f16* Kp  = Qp + (size_t)S_LEN * DIM;   // 24..28
  f16* Vt  = Kp + (size_t)S_LEN * DIM;   // 28..32
  f16* IDn = qh;                         // 0..8MB  [qh/kh dead after gemm_qkv]
  f16* C0  = vh;                         // 8..12MB [vh dead after gemm_qkv]
  f16* C1  = wqh;                        // 12..16MB [wqh/wkh dead]
  f16* Ct  = qh;                         // 0..4MB  [IDn dead after attn_ctx]

  dim3 b256(256);
  cvt_all<<<dim3(1024, 10), b256, 0, stream>>>(q, k, v, Wq, Wk, Wv, Wo,
                                               qh, kh, vh, wqh, wkh, wvh, woh);

  gemm_qkv<<<dim3(DIM / 64, S_LEN / 128, 3), b256, 0, stream>>>(
      qh, kh, vh, wqh, wkh, wvh, bq, bk, bv, Qp, Kp, Vt);

  hipMemsetAsync(out, 0, (size_t)S_LEN * DIM * sizeof(float), stream);

  attn_denom<<<dim3(S_LEN / 64, S_LEN / 64), b256, 0, stream>>>(Qp, Kp, IDn);
  attn_ctx<<<dim3(S_LEN / 64, NH, 2), b256, 0, stream>>>(Qp, Kp, Vt, IDn, C0, C1);

  const int n8 = S_LEN * DIM / 8;
  sum_halves<<<n8 / 256, b256, 0, stream>>>(C0, C1, Ct);

  gemm_out<<<dim3(DIM / 64, S_LEN / 128, 2), b256, 0, stream>>>(Ct, woh, bo, out);
}

// Round 9
// 209.236 us; speedup vs baseline: 1.1923x; 1.0214x over previous
//
#include <hip/hip_runtime.h>
#include <hip/hip_fp16.h>

// MHA with softmax over HEADS axis. R16: two mechanism-certain cuts on R15.
// (a) LDS bank-conflict fix for attn_ctx AND attn_denom: all K/V/Q tiles have
// 64B row stride -> b128 reads put 8 lanes on one bank quad (4.2M conflict
// cycles in ctx). XOR slot with (row>>1)&3, applied both-sides (swizzled
// global SOURCE col per rule 21 - the R8-verified pattern - linear gload dest,
// XOR'd read slot). Bit-identical values. (b) gemm_out: 64x64 tiles, grid
// (16,32), full-K, direct f32 stores + bias -> no split-K atomics, no memset.

typedef _Float16 f16;
typedef _Float16 f16x4 __attribute__((ext_vector_type(4)));
typedef _Float16 f16x8 __attribute__((ext_vector_type(8)));
typedef float    f32x4 __attribute__((ext_vector_type(4)));

#define S_LEN 2048
#define DIM   1024
#define NH    16
#define DK    64
// exp(s * 0.125) = exp2(s * log2(e)/8)
#define EXP2K 0.1803368801111244f

#define MFMA(a, b, c) __builtin_amdgcn_mfma_f32_16x16x32_f16(a, b, c, 0, 0, 0)

#define VM_WAIT0   asm volatile("s_waitcnt vmcnt(0)" ::: "memory")
#define WG_BARRIER asm volatile("s_barrier" ::: "memory")

typedef __attribute__((address_space(1))) void g_void;
typedef __attribute__((address_space(3))) void l_void;

static __device__ __forceinline__ void gload_lds16(const void* g, void* l) {
  __builtin_amdgcn_global_load_lds((g_void*)g, (l_void*)l, 16, 0, 0);
}

static __device__ __forceinline__ float exp_s(float s) {
  return __builtin_amdgcn_exp2f(s * EXP2K);  // identical in denom & ctx
}

// ---------------------------------------------------------------- merged cvt fp32->f16
__global__ __launch_bounds__(256) void cvt_all(
    const float* __restrict__ q, const float* __restrict__ k, const float* __restrict__ v,
    const float* __restrict__ Wq, const float* __restrict__ Wk, const float* __restrict__ Wv,
    const float* __restrict__ Wo, f16* __restrict__ qh, f16* __restrict__ kh,
    f16* __restrict__ vh, f16* __restrict__ wqh, f16* __restrict__ wkh,
    f16* __restrict__ wvh, f16* __restrict__ woh) {
  const size_t M = 1048576;
  const int seg = blockIdx.y;
  const float* src;
  f16* dst;
  switch (seg) {
    case 0: src = q;      dst = qh;      break;
    case 1: src = q + M;  dst = qh + M;  break;
    case 2: src = k;      dst = kh;      break;
    case 3: src = k + M;  dst = kh + M;  break;
    case 4: src = v;      dst = vh;      break;
    case 5: src = v + M;  dst = vh + M;  break;
    case 6: src = Wq;     dst = wqh;     break;
    case 7: src = Wk;     dst = wkh;     break;
    case 8: src = Wv;     dst = wvh;     break;
    default: src = Wo;    dst = woh;     break;
  }
  int i = blockIdx.x * 256 + threadIdx.x;
  float4 vv = ((const float4*)src)[i];
  f16x4 o = {(f16)vv.x, (f16)vv.y, (f16)vv.z, (f16)vv.w};
  ((f16x4*)dst)[i] = o;
}

// ---------------------------------------------------------------- Ct = C0 + C1 (f16, f32 math)
__global__ __launch_bounds__(256) void sum_halves(const f16* __restrict__ a,
                                                  const f16* __restrict__ b,
                                                  f16* __restrict__ o) {
  int i = blockIdx.x * 256 + threadIdx.x;
  f16x8 x = ((const f16x8*)a)[i];
  f16x8 y = ((const f16x8*)b)[i];
  f16x8 r;
#pragma unroll
  for (int j = 0; j < 8; j++) r[j] = (f16)((float)x[j] + (float)y[j]);
  ((f16x8*)o)[i] = r;
}

// ---------------------------------------------------------------- pipelined 128x64 GEMM core
static __device__ __forceinline__ void gemm32_core(const f16* __restrict__ X,
                                                   const f16* __restrict__ W,
                                                   int k0, int k1, int bm, int bn,
                                                   f16* As, f16* Bs,
                                                   f32x4 (&acc)[4][2]) {
  const int tid = threadIdx.x;
  const int wv = tid >> 6;
  const int lane = tid & 63;
  const int qd = lane >> 4;
  const int l16 = lane & 15;
  const int wm = (wv & 1) * 64;
  const int wn = (wv >> 1) * 32;
  const int lr4 = lane >> 2, lc4 = lane & 3;

  const f16* gA = X + (size_t)(bm + wv * 32 + lr4) * DIM + k0 + lc4 * 8;
  const f16* gB = W + (size_t)(bn + wv * 16 + lr4) * DIM + k0 + lc4 * 8;
  const int np = (k1 - k0) >> 5;

  // prologue: period 0 into buf 0
  gload_lds16(gA, As + (wv * 32) * 32);
  gload_lds16(gA + 16 * DIM, As + (wv * 32 + 16) * 32);
  gload_lds16(gB, Bs + (wv * 16) * 32);

#pragma unroll 2
  for (int t = 0; t < np; t++) {
    const int buf = t & 1;
    VM_WAIT0;
    WG_BARRIER;
    if (t + 1 < np) {
      const f16* gA1 = gA + (t + 1) * 32;
      const f16* gB1 = gB + (t + 1) * 32;
      f16* dA = As + (buf ^ 1) * (128 * 32);
      f16* dB = Bs + (buf ^ 1) * (64 * 32);
      gload_lds16(gA1, dA + (wv * 32) * 32);
      gload_lds16(gA1 + 16 * DIM, dA + (wv * 32 + 16) * 32);
      gload_lds16(gB1, dB + (wv * 16) * 32);
    }
    const f16* A = As + buf * (128 * 32);
    const f16* B = Bs + buf * (64 * 32);
    f16x8 bf[2];
#pragma unroll
    for (int ni = 0; ni < 2; ni++)
      bf[ni] = *(const f16x8*)&B[(wn + ni * 16 + l16) * 32 + qd * 8];
#pragma unroll
    for (int mi = 0; mi < 4; mi++) {
      f16x8 af = *(const f16x8*)&A[(wm + mi * 16 + l16) * 32 + qd * 8];
#pragma unroll
      for (int ni = 0; ni < 2; ni++)
        acc[mi][ni] = MFMA(af, bf[ni], acc[mi][ni]);
    }
  }
}

// ---------------------------------------------------------------- merged QKV proj
__global__ __launch_bounds__(256) void gemm_qkv(
    const f16* __restrict__ X0, const f16* __restrict__ X1, const f16* __restrict__ X2,
    const f16* __restrict__ W0, const f16* __restrict__ W1, const f16* __restrict__ W2,
    const float* __restrict__ b0, const float* __restrict__ b1, const float* __restrict__ b2,
    f16* __restrict__ o0, f16* __restrict__ o1, f16* __restrict__ o2) {
  __shared__ __align__(16) f16 As[2 * 128 * 32];
  __shared__ __align__(16) f16 Bs[2 * 64 * 32];
  const int z = blockIdx.z;
  const f16* X = z == 0 ? X0 : z == 1 ? X1 : X2;
  const f16* W = z == 0 ? W0 : z == 1 ? W1 : W2;
  const float* bias = z == 0 ? b0 : z == 1 ? b1 : b2;
  f16* outh = z == 0 ? o0 : z == 1 ? o1 : o2;

  const int bm = blockIdx.y * 128, bn = blockIdx.x * 64;
  f32x4 acc[4][2];
#pragma unroll
  for (int a = 0; a < 4; a++)
#pragma unroll
    for (int b = 0; b < 2; b++) acc[a][b] = (f32x4){0.f, 0.f, 0.f, 0.f};

  gemm32_core(X, W, 0, DIM, bm, bn, As, Bs, acc);

  const int tid = threadIdx.x;
  const int wv = tid >> 6, lane = tid & 63;
  const int qd = lane >> 4, l16 = lane & 15;
  const int wm = (wv & 1) * 64, wn = (wv >> 1) * 32;
#pragma unroll
  for (int mi = 0; mi < 4; mi++) {
#pragma unroll
    for (int ni = 0; ni < 2; ni++) {
      const int gm = bm + wm + mi * 16 + qd * 4;
      const int gn = bn + wn + ni * 16 + l16;
      const float bs = bias[gn];
      if (z == 2) {
        f16x4 o = {(f16)(acc[mi][ni][0] + bs), (f16)(acc[mi][ni][1] + bs),
                   (f16)(acc[mi][ni][2] + bs), (f16)(acc[mi][ni][3] + bs)};
        // Vt stored j-PERMUTED within each 32-block: storage[pi(j)] = V[j],
        // pi(gm) = (gm&~31) + ((gm>>2)&3)*8 + ((gm>>4)&1)*4 + (gm&3).
        const int pj = (gm & ~31) + ((gm >> 2) & 3) * 8 + ((gm >> 4) & 1) * 4;
        *(f16x4*)&outh[(size_t)gn * S_LEN + pj] = o;  // Vt[d][perm j]
      } else {
#pragma unroll
        for (int r = 0; r < 4; r++)
          outh[(size_t)(gm + r) * DIM + gn] = (f16)(acc[mi][ni][r] + bs);
      }
    }
  }
}

// ---------------------------------------------------------------- out GEMM 64x64, full-K
// grid (16, 32) = 512 blocks = 2/CU. No split-K -> direct f32 store + bias,
// no atomics, no memset. Per wave: 32x32 quadrant, 2 DMA + 4 MFMA / period.
__global__ __launch_bounds__(256) void gemm_out(const f16* __restrict__ X,
                                                const f16* __restrict__ W,
                                                const float* __restrict__ bias,
                                                float* __restrict__ outf) {
  __shared__ __align__(16) f16 As[2 * 64 * 32];
  __shared__ __align__(16) f16 Bs[2 * 64 * 32];
  const int tid = threadIdx.x;
  const int wv = tid >> 6;
  const int lane = tid & 63;
  const int qd = lane >> 4;
  const int l16 = lane & 15;
  const int wm = (wv & 1) * 32;
  const int wn = (wv >> 1) * 32;
  const int lr4 = lane >> 2, lc4 = lane & 3;
  const int bm = blockIdx.y * 64, bn = blockIdx.x * 64;

  const f16* gA = X + (size_t)(bm + wv * 16 + lr4) * DIM + lc4 * 8;
  const f16* gB = W + (size_t)(bn + wv * 16 + lr4) * DIM + lc4 * 8;

  f32x4 acc[2][2];
#pragma unroll
  for (int a = 0; a < 2; a++)
#pragma unroll
    for (int b = 0; b < 2; b++) acc[a][b] = (f32x4){0.f, 0.f, 0.f, 0.f};

  // prologue: period 0 into buf 0
  gload_lds16(gA, As + (wv * 16) * 32);
  gload_lds16(gB, Bs + (wv * 16) * 32);

#pragma unroll 2
  for (int t = 0; t < 32; t++) {
    const int buf = t & 1;
    VM_WAIT0;
    WG_BARRIER;
    if (t + 1 < 32) {
      gload_lds16(gA + (t + 1) * 32, As + (buf ^ 1) * (64 * 32) + (wv * 16) * 32);
      gload_lds16(gB + (t + 1) * 32, Bs + (buf ^ 1) * (64 * 32) + (wv * 16) * 32);
    }
    const f16* A = As + buf * (64 * 32);
    const f16* B = Bs + buf * (64 * 32);
    f16x8 bf[2];
#pragma unroll
    for (int ni = 0; ni < 2; ni++)
      bf[ni] = *(const f16x8*)&B[(wn + ni * 16 + l16) * 32 + qd * 8];
#pragma unroll
    for (int mi = 0; mi < 2; mi++) {
      f16x8 af = *(const f16x8*)&A[(wm + mi * 16 + l16) * 32 + qd * 8];
#pragma unroll
      for (int ni = 0; ni < 2; ni++)
        acc[mi][ni] = MFMA(af, bf[ni], acc[mi][ni]);
    }
  }

#pragma unroll
  for (int mi = 0; mi < 2; mi++) {
#pragma unroll
    for (int ni = 0; ni < 2; ni++) {
      const int gm = bm + wm + mi * 16 + qd * 4;
      const int gn = bn + wn + ni * 16 + l16;
      const float bs = bias[gn];
#pragma unroll
      for (int r = 0; r < 4; r++)
        outf[(size_t)(gm + r) * DIM + gn] = acc[mi][ni][r] + bs;
    }
  }
}

// ---------------------------------------------------------------- pass A: IDn = 1/sum_h exp
// 64x64 tile, grid 1024. IDn stored j-PERMUTED (same pi as Vt). Qs/Ks reads
// bank-conflict-free via both-sides XOR slot swizzle (source col swizzled,
// linear gload dest, XOR'd read slot) -- bit-identical values.
__global__ __launch_bounds__(256) void attn_denom(const f16* __restrict__ Qp,
                                                  const f16* __restrict__ Kp,
                                                  f16* __restrict__ IDn) {
  __shared__ __align__(16) f16 Qs[2][2][64 * 32];  // [buf][kk][row][32]
  __shared__ __align__(16) f16 Ks[2][2][64 * 32];
  const int tid = threadIdx.x;
  const int wv = tid >> 6;
  const int lane = tid & 63;
  const int qd = lane >> 4;
  const int l16 = lane & 15;
  const int wm = (wv & 1) * 32, wn = (wv >> 1) * 32;
  const int bi = blockIdx.y * 64, bj = blockIdx.x * 64;
  const int lr4 = lane >> 2, lc4 = lane & 3;
  const int kkw = wv & 1;
  const int q0 = (wv >> 1) * 2;
  const int ssw = (lc4 ^ ((lr4 >> 1) & 3)) * 8;  // swizzled source col slot
  const int rsw = (qd ^ ((l16 >> 1) & 3)) * 8;   // swizzled read slot

  f32x4 dsum[2][2];
#pragma unroll
  for (int a = 0; a < 2; a++)
#pragma unroll
    for (int b = 0; b < 2; b++) dsum[a][b] = (f32x4){0.f, 0.f, 0.f, 0.f};

  // prologue: head 0 -> buf 0
  {
    const f16* gq = Qp + (size_t)(bi + q0 * 16 + lr4) * DIM + kkw * 32 + ssw;
    const f16* gk = Kp + (size_t)(bj + q0 * 16 + lr4) * DIM + kkw * 32 + ssw;
#pragma unroll
    for (int t = 0; t < 2; t++) {
      gload_lds16(gq + (size_t)t * 16 * DIM, &Qs[0][kkw][(q0 + t) * 16 * 32]);
      gload_lds16(gk + (size_t)t * 16 * DIM, &Ks[0][kkw][(q0 + t) * 16 * 32]);
    }
  }

#pragma unroll 2
  for (int h = 0; h < NH; h++) {
    const int buf = h & 1;
    VM_WAIT0;
    WG_BARRIER;
    if (h + 1 < NH) {
      const f16* gq = Qp + (size_t)(bi + q0 * 16 + lr4) * DIM + (h + 1) * DK + kkw * 32 + ssw;
      const f16* gk = Kp + (size_t)(bj + q0 * 16 + lr4) * DIM + (h + 1) * DK + kkw * 32 + ssw;
#pragma unroll
      for (int t = 0; t < 2; t++) {
        gload_lds16(gq + (size_t)t * 16 * DIM, &Qs[buf ^ 1][kkw][(q0 + t) * 16 * 32]);
        gload_lds16(gk + (size_t)t * 16 * DIM, &Ks[buf ^ 1][kkw][(q0 + t) * 16 * 32]);
      }
    }

#pragma unroll
    for (int mi = 0; mi < 2; mi++) {
      f16x8 af0 = *(const f16x8*)&Qs[buf][0][(wm + mi * 16 + l16) * 32 + rsw];
      f16x8 af1 = *(const f16x8*)&Qs[buf][1][(wm + mi * 16 + l16) * 32 + rsw];
#pragma unroll
      for (int ni = 0; ni < 2; ni++) {
        f16x8 bf0 = *(const f16x8*)&Ks[buf][0][(wn + ni * 16 + l16) * 32 + rsw];
        f16x8 bf1 = *(const f16x8*)&Ks[buf][1][(wn + ni * 16 + l16) * 32 + rsw];
        f32x4 s = {0.f, 0.f, 0.f, 0.f};
        s = MFMA(af0, bf0, s);  // kk order identical to attn_ctx
        s = MFMA(af1, bf1, s);
#pragma unroll
        for (int r = 0; r < 4; r++) dsum[mi][ni][r] += exp_s(s[r]);
      }
    }
  }
#pragma unroll
  for (int mi = 0; mi < 2; mi++)
#pragma unroll
    for (int ni = 0; ni < 2; ni++)
#pragma unroll
      for (int r = 0; r < 4; r++) {
        const int gi = bi + wm + mi * 16 + qd * 4 + r;
        const int gj = bj + wn + ni * 16 + l16;
        // j-permuted store (same pi as Vt): IDnP[pi(gj)] = 1/dsum(gj)
        const int pj = (gj & ~31) + ((gj >> 2) & 3) * 8 + ((gj >> 4) & 1) * 4 + (gj & 3);
        IDn[(size_t)gi * S_LEN + pj] = (f16)(1.f / dsum[mi][ni][r]);
      }
}

// ---------------------------------------------------------------- pass B: ctx
// grid (32, 16, 2) = 1024 blocks. R15 body + both-sides XOR slot swizzle on
// Ks/Vs (source col swizzled, linear dest, XOR'd read) -> 2-way max on the
// b128 fragment reads. Direct f16 stores to disjoint half-buffers.
__global__ __launch_bounds__(256, 8) void attn_ctx(const f16* __restrict__ Qp,
                                                   const f16* __restrict__ Kp,
                                                   const f16* __restrict__ Vt,
                                                   const f16* __restrict__ IDn,
                                                   f16* __restrict__ C0,
                                                   f16* __restrict__ C1) {
  __shared__ __align__(16) f16 Ks[2][2][32 * 32];  // [buf][kk][j32][dk32] 8KB
  __shared__ __align__(16) f16 Vs[2][64 * 32];     // [buf][d64][j32 perm]  8KB
  const int tid = threadIdx.x;
  const int wv = tid >> 6;
  const int lane = tid & 63;
  const int qd = lane >> 4;
  const int l16 = lane & 15;
  // XCD-aware remap over flat 1024: 128-block chunks/XCD.
  const int flat = blockIdx.x + (blockIdx.y << 5) + (blockIdx.z << 9);
  const int nf = ((flat & 7) << 7) + (flat >> 3);
  const int h = (nf >> 5) & 15;
  const int iw = (nf & 31) * 64 + wv * 16;
  const int z = nf >> 9;
  const int jb = z * 1024;
  f16* Cz = z == 0 ? C0 : C1;
  const int lr4 = lane >> 2, lc4 = lane & 3;
  const int kkw = wv & 1;
  const int rhw = wv >> 1;
  const int ssw = (lc4 ^ ((lr4 >> 1) & 3)) * 8;  // swizzled source col slot
  const int rsw = (qd ^ ((l16 >> 1) & 3)) * 8;   // swizzled read slot

  // Q fragment (B-operand of swapped QK^T), 1 mi
  f16x8 aq[2];
#pragma unroll
  for (int kk = 0; kk < 2; kk++)
    aq[kk] = *(const f16x8*)(Qp + (size_t)(iw + l16) * DIM + h * DK + kk * 32 + qd * 8);

  f32x4 acc[4];
#pragma unroll
  for (int b = 0; b < 4; b++) acc[b] = (f32x4){0.f, 0.f, 0.f, 0.f};

  f16x8 idn[2];  // [buf] permuted-IDn, elementwise aligned with P

  // one group = 3 vmem ops/wave: K gload + V gload + idn f16x8
  auto issue = [&](int tt, int pb) {
    const int j1 = jb + tt * 32;
    gload_lds16(Kp + (size_t)(j1 + rhw * 16 + lr4) * DIM + h * DK + kkw * 32 + ssw,
                &Ks[pb][kkw][(rhw * 16) * 32]);
    gload_lds16(Vt + (size_t)(h * DK + wv * 16 + lr4) * S_LEN + j1 + ssw,
                &Vs[pb][(wv * 16) * 32]);
    idn[pb] = *(const f16x8*)(IDn + (size_t)(iw + l16) * S_LEN + j1 + qd * 8);
  };

  issue(0, 0);

#pragma unroll 2
  for (int t = 0; t < 32; t++) {
    const int buf = t & 1;
    VM_WAIT0;
    WG_BARRIER;
    if (t + 1 < 32) issue(t + 1, buf ^ 1);

    // K fragments (A-operand: row=j, k=dk), swizzled read slot
    f16x8 bk[2][2];
#pragma unroll
    for (int ni = 0; ni < 2; ni++)
#pragma unroll
      for (int kk = 0; kk < 2; kk++)
        bk[ni][kk] = *(const f16x8*)&Ks[buf][kk][(ni * 16 + l16) * 32 + rsw];

    // swapped QK^T + exp + permuted-IDn scale, all lane-local
    f32x4 st0 = {0.f, 0.f, 0.f, 0.f};
    f32x4 st1 = {0.f, 0.f, 0.f, 0.f};
    st0 = MFMA(bk[0][0], aq[0], st0);  // kk order identical to attn_denom
    st0 = MFMA(bk[0][1], aq[1], st0);
    st1 = MFMA(bk[1][0], aq[0], st1);
    st1 = MFMA(bk[1][1], aq[1], st1);
    f16x8 p;
#pragma unroll
    for (int r = 0; r < 4; r++) p[r] = (f16)(exp_s(st0[r]) * (float)idn[buf][r]);
#pragma unroll
    for (int r = 0; r < 4; r++) p[4 + r] = (f16)(exp_s(st1[r]) * (float)idn[buf][4 + r]);

    // PV: B-operand b128 from permuted Vs, swizzled read slot
    f16x8 bv[4];
#pragma unroll
    for (int nd = 0; nd < 4; nd++)
      bv[nd] = *(const f16x8*)&Vs[buf][(nd * 16 + l16) * 32 + rsw];
#pragma unroll
    for (int nd = 0; nd < 4; nd++)
      acc[nd] = MFMA(p, bv[nd], acc[nd]);
  }

  // direct f16 store (disjoint per z) — no atomics
#pragma unroll
  for (int nd = 0; nd < 4; nd++)
#pragma unroll
    for (int r = 0; r < 4; r++)
      Cz[(size_t)(iw + qd * 4 + r) * DIM + h * DK + nd * 16 + l16] = (f16)acc[nd][r];
}

// ---------------------------------------------------------------- launcher
extern "C" void kernel_launch(void* const* d_in, const int* in_sizes, int n_in,
                              void* d_out, int out_size, void* d_ws, size_t ws_size,
                              hipStream_t stream) {
  const float* q  = (const float*)d_in[0];
  const float* k  = (const float*)d_in[1];
  const float* v  = (const float*)d_in[2];
  const float* Wq = (const float*)d_in[3];
  const float* bq = (const float*)d_in[4];
  const float* Wk = (const float*)d_in[5];
  const float* bk = (const float*)d_in[6];
  const float* Wv = (const float*)d_in[7];
  const float* bv = (const float*)d_in[8];
  const float* Wo = (const float*)d_in[9];
  const float* bo = (const float*)d_in[10];
  float* out = (float*)d_out;

  f16* w = (f16*)d_ws;
  f16* qh  = w;                          // 0..4MB
  f16* kh  = qh + (size_t)S_LEN * DIM;   // 4..8
  f16* vh  = kh + (size_t)S_LEN * DIM;   // 8..12
  f16* wqh = vh + (size_t)S_LEN * DIM;   // 12..14
  f16* wkh = wqh + (size_t)DIM * DIM;    // 14..16
  f16* wvh = wkh + (size_t)DIM * DIM;    // 16..18
  f16* woh = wvh + (size_t)DIM * DIM;    // 18..20
  f16* Qp  = woh + (size_t)DIM * DIM;    // 20..24
  f16* Kp  = Qp + (size_t)S_LEN * DIM;   // 24..28
  f16* Vt  = Kp + (size_t)S_LEN * DIM;   // 28..32
  f16* IDn = qh;                         // 0..8MB  [qh/kh dead after gemm_qkv]
  f16* C0  = vh;                         // 8..12MB [vh dead after gemm_qkv]
  f16* C1  = wqh;                        // 12..16MB [wqh/wkh dead]
  f16* Ct  = qh;                         // 0..4MB  [IDn dead after attn_ctx]

  dim3 b256(256);
  cvt_all<<<dim3(1024, 10), b256, 0, stream>>>(q, k, v, Wq, Wk, Wv, Wo,
                                               qh, kh, vh, wqh, wkh, wvh, woh);

  gemm_qkv<<<dim3(DIM / 64, S_LEN / 128, 3), b256, 0, stream>>>(
      qh, kh, vh, wqh, wkh, wvh, bq, bk, bv, Qp, Kp, Vt);

  attn_denom<<<dim3(S_LEN / 64, S_LEN / 64), b256, 0, stream>>>(Qp, Kp, IDn);
  attn_ctx<<<dim3(S_LEN / 64, NH, 2), b256, 0, stream>>>(Qp, Kp, Vt, IDn, C0, C1);

  const int n8 = S_LEN * DIM / 8;
  sum_halves<<<n8 / 256, b256, 0, stream>>>(C0, C1, Ct);

  gemm_out<<<dim3(DIM / 64, S_LEN / 64), b256, 0, stream>>>(Ct, woh, bo, out);
}

// Round 10
// 205.216 us; speedup vs baseline: 1.2156x; 1.0196x over previous
//
#include <hip/hip_runtime.h>
#include <hip/hip_fp16.h>

// MHA with softmax over HEADS axis. R17: (a) attn_ctx KVBLK=64 — half the
// per-block iteration count (16 vs 32) at unchanged 4 blocks/CU: tests the
// per-iteration fixed cost (vmcnt drain + barrier + issue) directly. V tile
// is now 64x64 (128B rows) -> 3-bit XOR slot swizzle (R10-verified pattern);
// K keeps R16's 2-bit swizzle. (b) attn_denom gets the XCD remap (4 bi-tiles
// x all bj per XCD; 128 co-resident blocks -> L2 K-reuse x4, Q x32).

typedef _Float16 f16;
typedef _Float16 f16x4 __attribute__((ext_vector_type(4)));
typedef _Float16 f16x8 __attribute__((ext_vector_type(8)));
typedef float    f32x4 __attribute__((ext_vector_type(4)));

#define S_LEN 2048
#define DIM   1024
#define NH    16
#define DK    64
// exp(s * 0.125) = exp2(s * log2(e)/8)
#define EXP2K 0.1803368801111244f

#define MFMA(a, b, c) __builtin_amdgcn_mfma_f32_16x16x32_f16(a, b, c, 0, 0, 0)

#define VM_WAIT0   asm volatile("s_waitcnt vmcnt(0)" ::: "memory")
#define WG_BARRIER asm volatile("s_barrier" ::: "memory")

typedef __attribute__((address_space(1))) void g_void;
typedef __attribute__((address_space(3))) void l_void;

static __device__ __forceinline__ void gload_lds16(const void* g, void* l) {
  __builtin_amdgcn_global_load_lds((g_void*)g, (l_void*)l, 16, 0, 0);
}

static __device__ __forceinline__ float exp_s(float s) {
  return __builtin_amdgcn_exp2f(s * EXP2K);  // identical in denom & ctx
}

// ---------------------------------------------------------------- merged cvt fp32->f16
__global__ __launch_bounds__(256) void cvt_all(
    const float* __restrict__ q, const float* __restrict__ k, const float* __restrict__ v,
    const float* __restrict__ Wq, const float* __restrict__ Wk, const float* __restrict__ Wv,
    const float* __restrict__ Wo, f16* __restrict__ qh, f16* __restrict__ kh,
    f16* __restrict__ vh, f16* __restrict__ wqh, f16* __restrict__ wkh,
    f16* __restrict__ wvh, f16* __restrict__ woh) {
  const size_t M = 1048576;
  const int seg = blockIdx.y;
  const float* src;
  f16* dst;
  switch (seg) {
    case 0: src = q;      dst = qh;      break;
    case 1: src = q + M;  dst = qh + M;  break;
    case 2: src = k;      dst = kh;      break;
    case 3: src = k + M;  dst = kh + M;  break;
    case 4: src = v;      dst = vh;      break;
    case 5: src = v + M;  dst = vh + M;  break;
    case 6: src = Wq;     dst = wqh;     break;
    case 7: src = Wk;     dst = wkh;     break;
    case 8: src = Wv;     dst = wvh;     break;
    default: src = Wo;    dst = woh;     break;
  }
  int i = blockIdx.x * 256 + threadIdx.x;
  float4 vv = ((const float4*)src)[i];
  f16x4 o = {(f16)vv.x, (f16)vv.y, (f16)vv.z, (f16)vv.w};
  ((f16x4*)dst)[i] = o;
}

// ---------------------------------------------------------------- Ct = C0 + C1 (f16, f32 math)
__global__ __launch_bounds__(256) void sum_halves(const f16* __restrict__ a,
                                                  const f16* __restrict__ b,
                                                  f16* __restrict__ o) {
  int i = blockIdx.x * 256 + threadIdx.x;
  f16x8 x = ((const f16x8*)a)[i];
  f16x8 y = ((const f16x8*)b)[i];
  f16x8 r;
#pragma unroll
  for (int j = 0; j < 8; j++) r[j] = (f16)((float)x[j] + (float)y[j]);
  ((f16x8*)o)[i] = r;
}

// ---------------------------------------------------------------- pipelined 128x64 GEMM core
static __device__ __forceinline__ void gemm32_core(const f16* __restrict__ X,
                                                   const f16* __restrict__ W,
                                                   int k0, int k1, int bm, int bn,
                                                   f16* As, f16* Bs,
                                                   f32x4 (&acc)[4][2]) {
  const int tid = threadIdx.x;
  const int wv = tid >> 6;
  const int lane = tid & 63;
  const int qd = lane >> 4;
  const int l16 = lane & 15;
  const int wm = (wv & 1) * 64;
  const int wn = (wv >> 1) * 32;
  const int lr4 = lane >> 2, lc4 = lane & 3;

  const f16* gA = X + (size_t)(bm + wv * 32 + lr4) * DIM + k0 + lc4 * 8;
  const f16* gB = W + (size_t)(bn + wv * 16 + lr4) * DIM + k0 + lc4 * 8;
  const int np = (k1 - k0) >> 5;

  // prologue: period 0 into buf 0
  gload_lds16(gA, As + (wv * 32) * 32);
  gload_lds16(gA + 16 * DIM, As + (wv * 32 + 16) * 32);
  gload_lds16(gB, Bs + (wv * 16) * 32);

#pragma unroll 2
  for (int t = 0; t < np; t++) {
    const int buf = t & 1;
    VM_WAIT0;
    WG_BARRIER;
    if (t + 1 < np) {
      const f16* gA1 = gA + (t + 1) * 32;
      const f16* gB1 = gB + (t + 1) * 32;
      f16* dA = As + (buf ^ 1) * (128 * 32);
      f16* dB = Bs + (buf ^ 1) * (64 * 32);
      gload_lds16(gA1, dA + (wv * 32) * 32);
      gload_lds16(gA1 + 16 * DIM, dA + (wv * 32 + 16) * 32);
      gload_lds16(gB1, dB + (wv * 16) * 32);
    }
    const f16* A = As + buf * (128 * 32);
    const f16* B = Bs + buf * (64 * 32);
    f16x8 bf[2];
#pragma unroll
    for (int ni = 0; ni < 2; ni++)
      bf[ni] = *(const f16x8*)&B[(wn + ni * 16 + l16) * 32 + qd * 8];
#pragma unroll
    for (int mi = 0; mi < 4; mi++) {
      f16x8 af = *(const f16x8*)&A[(wm + mi * 16 + l16) * 32 + qd * 8];
#pragma unroll
      for (int ni = 0; ni < 2; ni++)
        acc[mi][ni] = MFMA(af, bf[ni], acc[mi][ni]);
    }
  }
}

// ---------------------------------------------------------------- merged QKV proj
__global__ __launch_bounds__(256) void gemm_qkv(
    const f16* __restrict__ X0, const f16* __restrict__ X1, const f16* __restrict__ X2,
    const f16* __restrict__ W0, const f16* __restrict__ W1, const f16* __restrict__ W2,
    const float* __restrict__ b0, const float* __restrict__ b1, const float* __restrict__ b2,
    f16* __restrict__ o0, f16* __restrict__ o1, f16* __restrict__ o2) {
  __shared__ __align__(16) f16 As[2 * 128 * 32];
  __shared__ __align__(16) f16 Bs[2 * 64 * 32];
  const int z = blockIdx.z;
  const f16* X = z == 0 ? X0 : z == 1 ? X1 : X2;
  const f16* W = z == 0 ? W0 : z == 1 ? W1 : W2;
  const float* bias = z == 0 ? b0 : z == 1 ? b1 : b2;
  f16* outh = z == 0 ? o0 : z == 1 ? o1 : o2;

  const int bm = blockIdx.y * 128, bn = blockIdx.x * 64;
  f32x4 acc[4][2];
#pragma unroll
  for (int a = 0; a < 4; a++)
#pragma unroll
    for (int b = 0; b < 2; b++) acc[a][b] = (f32x4){0.f, 0.f, 0.f, 0.f};

  gemm32_core(X, W, 0, DIM, bm, bn, As, Bs, acc);

  const int tid = threadIdx.x;
  const int wv = tid >> 6, lane = tid & 63;
  const int qd = lane >> 4, l16 = lane & 15;
  const int wm = (wv & 1) * 64, wn = (wv >> 1) * 32;
#pragma unroll
  for (int mi = 0; mi < 4; mi++) {
#pragma unroll
    for (int ni = 0; ni < 2; ni++) {
      const int gm = bm + wm + mi * 16 + qd * 4;
      const int gn = bn + wn + ni * 16 + l16;
      const float bs = bias[gn];
      if (z == 2) {
        f16x4 o = {(f16)(acc[mi][ni][0] + bs), (f16)(acc[mi][ni][1] + bs),
                   (f16)(acc[mi][ni][2] + bs), (f16)(acc[mi][ni][3] + bs)};
        // Vt stored j-PERMUTED within each 32-block: storage[pi(j)] = V[j],
        // pi(gm) = (gm&~31) + ((gm>>2)&3)*8 + ((gm>>4)&1)*4 + (gm&3).
        const int pj = (gm & ~31) + ((gm >> 2) & 3) * 8 + ((gm >> 4) & 1) * 4;
        *(f16x4*)&outh[(size_t)gn * S_LEN + pj] = o;  // Vt[d][perm j]
      } else {
#pragma unroll
        for (int r = 0; r < 4; r++)
          outh[(size_t)(gm + r) * DIM + gn] = (f16)(acc[mi][ni][r] + bs);
      }
    }
  }
}

// ---------------------------------------------------------------- out GEMM 64x64, full-K
__global__ __launch_bounds__(256) void gemm_out(const f16* __restrict__ X,
                                                const f16* __restrict__ W,
                                                const float* __restrict__ bias,
                                                float* __restrict__ outf) {
  __shared__ __align__(16) f16 As[2 * 64 * 32];
  __shared__ __align__(16) f16 Bs[2 * 64 * 32];
  const int tid = threadIdx.x;
  const int wv = tid >> 6;
  const int lane = tid & 63;
  const int qd = lane >> 4;
  const int l16 = lane & 15;
  const int wm = (wv & 1) * 32;
  const int wn = (wv >> 1) * 32;
  const int lr4 = lane >> 2, lc4 = lane & 3;
  const int bm = blockIdx.y * 64, bn = blockIdx.x * 64;

  const f16* gA = X + (size_t)(bm + wv * 16 + lr4) * DIM + lc4 * 8;
  const f16* gB = W + (size_t)(bn + wv * 16 + lr4) * DIM + lc4 * 8;

  f32x4 acc[2][2];
#pragma unroll
  for (int a = 0; a < 2; a++)
#pragma unroll
    for (int b = 0; b < 2; b++) acc[a][b] = (f32x4){0.f, 0.f, 0.f, 0.f};

  // prologue: period 0 into buf 0
  gload_lds16(gA, As + (wv * 16) * 32);
  gload_lds16(gB, Bs + (wv * 16) * 32);

#pragma unroll 2
  for (int t = 0; t < 32; t++) {
    const int buf = t & 1;
    VM_WAIT0;
    WG_BARRIER;
    if (t + 1 < 32) {
      gload_lds16(gA + (t + 1) * 32, As + (buf ^ 1) * (64 * 32) + (wv * 16) * 32);
      gload_lds16(gB + (t + 1) * 32, Bs + (buf ^ 1) * (64 * 32) + (wv * 16) * 32);
    }
    const f16* A = As + buf * (64 * 32);
    const f16* B = Bs + buf * (64 * 32);
    f16x8 bf[2];
#pragma unroll
    for (int ni = 0; ni < 2; ni++)
      bf[ni] = *(const f16x8*)&B[(wn + ni * 16 + l16) * 32 + qd * 8];
#pragma unroll
    for (int mi = 0; mi < 2; mi++) {
      f16x8 af = *(const f16x8*)&A[(wm + mi * 16 + l16) * 32 + qd * 8];
#pragma unroll
      for (int ni = 0; ni < 2; ni++)
        acc[mi][ni] = MFMA(af, bf[ni], acc[mi][ni]);
    }
  }

#pragma unroll
  for (int mi = 0; mi < 2; mi++) {
#pragma unroll
    for (int ni = 0; ni < 2; ni++) {
      const int gm = bm + wm + mi * 16 + qd * 4;
      const int gn = bn + wn + ni * 16 + l16;
      const float bs = bias[gn];
#pragma unroll
      for (int r = 0; r < 4; r++)
        outf[(size_t)(gm + r) * DIM + gn] = acc[mi][ni][r] + bs;
    }
  }
}

// ---------------------------------------------------------------- pass A: IDn = 1/sum_h exp
// 64x64 tile, grid 1024, XCD-remapped (4 bi-tiles x all bj per XCD). IDn
// stored j-PERMUTED (same pi as Vt). Qs/Ks reads conflict-free via both-sides
// XOR slot swizzle -- bit-identical values.
__global__ __launch_bounds__(256) void attn_denom(const f16* __restrict__ Qp,
                                                  const f16* __restrict__ Kp,
                                                  f16* __restrict__ IDn) {
  __shared__ __align__(16) f16 Qs[2][2][64 * 32];  // [buf][kk][row][32]
  __shared__ __align__(16) f16 Ks[2][2][64 * 32];
  const int tid = threadIdx.x;
  const int wv = tid >> 6;
  const int lane = tid & 63;
  const int qd = lane >> 4;
  const int l16 = lane & 15;
  const int wm = (wv & 1) * 32, wn = (wv >> 1) * 32;
  // XCD remap: xcd = flat&7 owns nf in [xcd*128, xcd*128+128) = 4 bi-tiles
  // x all 32 bj -> 128 co-resident blocks/XCD share K tiles x4, Q x32 in L2.
  const int flat = blockIdx.x + (blockIdx.y << 5);
  const int nf = ((flat & 7) << 7) + (flat >> 3);
  const int bi = (nf >> 5) * 64, bj = (nf & 31) * 64;
  const int lr4 = lane >> 2, lc4 = lane & 3;
  const int kkw = wv & 1;
  const int q0 = (wv >> 1) * 2;
  const int ssw = (lc4 ^ ((lr4 >> 1) & 3)) * 8;  // swizzled source col slot
  const int rsw = (qd ^ ((l16 >> 1) & 3)) * 8;   // swizzled read slot

  f32x4 dsum[2][2];
#pragma unroll
  for (int a = 0; a < 2; a++)
#pragma unroll
    for (int b = 0; b < 2; b++) dsum[a][b] = (f32x4){0.f, 0.f, 0.f, 0.f};

  // prologue: head 0 -> buf 0
  {
    const f16* gq = Qp + (size_t)(bi + q0 * 16 + lr4) * DIM + kkw * 32 + ssw;
    const f16* gk = Kp + (size_t)(bj + q0 * 16 + lr4) * DIM + kkw * 32 + ssw;
#pragma unroll
    for (int t = 0; t < 2; t++) {
      gload_lds16(gq + (size_t)t * 16 * DIM, &Qs[0][kkw][(q0 + t) * 16 * 32]);
      gload_lds16(gk + (size_t)t * 16 * DIM, &Ks[0][kkw][(q0 + t) * 16 * 32]);
    }
  }

#pragma unroll 2
  for (int h = 0; h < NH; h++) {
    const int buf = h & 1;
    VM_WAIT0;
    WG_BARRIER;
    if (h + 1 < NH) {
      const f16* gq = Qp + (size_t)(bi + q0 * 16 + lr4) * DIM + (h + 1) * DK + kkw * 32 + ssw;
      const f16* gk = Kp + (size_t)(bj + q0 * 16 + lr4) * DIM + (h + 1) * DK + kkw * 32 + ssw;
#pragma unroll
      for (int t = 0; t < 2; t++) {
        gload_lds16(gq + (size_t)t * 16 * DIM, &Qs[buf ^ 1][kkw][(q0 + t) * 16 * 32]);
        gload_lds16(gk + (size_t)t * 16 * DIM, &Ks[buf ^ 1][kkw][(q0 + t) * 16 * 32]);
      }
    }

#pragma unroll
    for (int mi = 0; mi < 2; mi++) {
      f16x8 af0 = *(const f16x8*)&Qs[buf][0][(wm + mi * 16 + l16) * 32 + rsw];
      f16x8 af1 = *(const f16x8*)&Qs[buf][1][(wm + mi * 16 + l16) * 32 + rsw];
#pragma unroll
      for (int ni = 0; ni < 2; ni++) {
        f16x8 bf0 = *(const f16x8*)&Ks[buf][0][(wn + ni * 16 + l16) * 32 + rsw];
        f16x8 bf1 = *(const f16x8*)&Ks[buf][1][(wn + ni * 16 + l16) * 32 + rsw];
        f32x4 s = {0.f, 0.f, 0.f, 0.f};
        s = MFMA(af0, bf0, s);  // kk order identical to attn_ctx
        s = MFMA(af1, bf1, s);
#pragma unroll
        for (int r = 0; r < 4; r++) dsum[mi][ni][r] += exp_s(s[r]);
      }
    }
  }
#pragma unroll
  for (int mi = 0; mi < 2; mi++)
#pragma unroll
    for (int ni = 0; ni < 2; ni++)
#pragma unroll
      for (int r = 0; r < 4; r++) {
        const int gi = bi + wm + mi * 16 + qd * 4 + r;
        const int gj = bj + wn + ni * 16 + l16;
        // j-permuted store (same pi as Vt): IDnP[pi(gj)] = 1/dsum(gj)
        const int pj = (gj & ~31) + ((gj >> 2) & 3) * 8 + ((gj >> 4) & 1) * 4 + (gj & 3);
        IDn[(size_t)gi * S_LEN + pj] = (f16)(1.f / dsum[mi][ni][r]);
      }
}

// ---------------------------------------------------------------- pass B: ctx
// grid (32, 16, 2) = 1024 blocks = 4/CU. KVBLK=64: 16 iterations (half the
// vmcnt+barrier events of R16), 16 MFMA/iter. K: R16 2-bit XOR swizzle;
// V 64x64 (128B rows): 3-bit XOR slot swizzle (R10-verified). Direct f16
// stores to disjoint half-buffers.
__global__ __launch_bounds__(256, 4) void attn_ctx(const f16* __restrict__ Qp,
                                                   const f16* __restrict__ Kp,
                                                   const f16* __restrict__ Vt,
                                                   const f16* __restrict__ IDn,
                                                   f16* __restrict__ C0,
                                                   f16* __restrict__ C1) {
  __shared__ __align__(16) f16 Ks[2][2][64 * 32];  // [buf][kk][j64][dk32] 16KB
  __shared__ __align__(16) f16 Vs[2][64 * 64];     // [buf][d64][j64 perm]  16KB
  const int tid = threadIdx.x;
  const int wv = tid >> 6;
  const int lane = tid & 63;
  const int qd = lane >> 4;
  const int l16 = lane & 15;
  // XCD-aware remap over flat 1024: 128-block chunks/XCD.
  const int flat = blockIdx.x + (blockIdx.y << 5) + (blockIdx.z << 9);
  const int nf = ((flat & 7) << 7) + (flat >> 3);
  const int h = (nf >> 5) & 15;
  const int iw = (nf & 31) * 64 + wv * 16;
  const int z = nf >> 9;
  const int jb = z * 1024;
  f16* Cz = z == 0 ? C0 : C1;
  const int lr4 = lane >> 2, lc4 = lane & 3;
  const int lr8 = lane >> 3, lc8 = lane & 7;
  const int kkw = wv & 1;
  const int rhw = wv >> 1;
  const int ssw = (lc4 ^ ((lr4 >> 1) & 3)) * 8;  // K: swizzled source col slot
  const int rsw = (qd ^ ((l16 >> 1) & 3)) * 8;   // K: swizzled read slot
  const int l7 = l16 & 7;                        // V: 3-bit row XOR key

  // Q fragment (B-operand of swapped QK^T), 1 mi
  f16x8 aq[2];
#pragma unroll
  for (int kk = 0; kk < 2; kk++)
    aq[kk] = *(const f16x8*)(Qp + (size_t)(iw + l16) * DIM + h * DK + kk * 32 + qd * 8);

  f32x4 acc[4];
#pragma unroll
  for (int b = 0; b < 4; b++) acc[b] = (f32x4){0.f, 0.f, 0.f, 0.f};

  f16x8 idn[2][2];  // [buf][js] permuted-IDn, elementwise aligned with P

  // one group = 6 vmem ops/wave: 2 K gload + 2 V gload + 2 idn f16x8
  auto issue = [&](int tt, int pb) {
    const int j1 = jb + tt * 64;
    const f16* gk = Kp + (size_t)(j1 + rhw * 16 + lr4) * DIM + h * DK + kkw * 32 + ssw;
    gload_lds16(gk, &Ks[pb][kkw][(rhw * 16) * 32]);
    gload_lds16(gk + (size_t)32 * DIM, &Ks[pb][kkw][(rhw * 16 + 32) * 32]);
    // V: dest linear; source slot XOR'd by (d&7)=lr8 (3-bit, both gloads)
    const f16* gv = Vt + (size_t)(h * DK + wv * 16 + lr8) * S_LEN + j1 + (lc8 ^ lr8) * 8;
    gload_lds16(gv, &Vs[pb][(wv * 16) * 64]);
    gload_lds16(gv + (size_t)8 * S_LEN, &Vs[pb][(wv * 16 + 8) * 64]);
#pragma unroll
    for (int js = 0; js < 2; js++)
      idn[pb][js] = *(const f16x8*)(IDn + (size_t)(iw + l16) * S_LEN + j1 + js * 32 + qd * 8);
  };

  issue(0, 0);

#pragma unroll 2
  for (int t = 0; t < 16; t++) {
    const int buf = t & 1;
    VM_WAIT0;
    WG_BARRIER;
    if (t + 1 < 16) issue(t + 1, buf ^ 1);

    // per js-subblock: QK^T (swapped) + exp + permuted-IDn scale, lane-local
    f16x8 pa[2];
#pragma unroll
    for (int js = 0; js < 2; js++) {
      f16x8 bk0[2], bk1[2];  // ni = js*2, js*2+1
#pragma unroll
      for (int kk = 0; kk < 2; kk++) {
        bk0[kk] = *(const f16x8*)&Ks[buf][kk][((js * 2) * 16 + l16) * 32 + rsw];
        bk1[kk] = *(const f16x8*)&Ks[buf][kk][((js * 2 + 1) * 16 + l16) * 32 + rsw];
      }
      f32x4 st0 = {0.f, 0.f, 0.f, 0.f};
      f32x4 st1 = {0.f, 0.f, 0.f, 0.f};
      st0 = MFMA(bk0[0], aq[0], st0);  // kk order identical to attn_denom
      st0 = MFMA(bk0[1], aq[1], st0);
      st1 = MFMA(bk1[0], aq[0], st1);
      st1 = MFMA(bk1[1], aq[1], st1);
      f16x8 p;
#pragma unroll
      for (int r = 0; r < 4; r++) p[r] = (f16)(exp_s(st0[r]) * (float)idn[buf][js][r]);
#pragma unroll
      for (int r = 0; r < 4; r++) p[4 + r] = (f16)(exp_s(st1[r]) * (float)idn[buf][js][4 + r]);
      pa[js] = p;
    }

    // PV: B-operand b128 from permuted Vs; read slot (js*4+qd) ^ (row&7)
#pragma unroll
    for (int js = 0; js < 2; js++) {
#pragma unroll
      for (int nd = 0; nd < 4; nd++) {
        f16x8 bv = *(const f16x8*)&Vs[buf][(nd * 16 + l16) * 64 +
                                          (((js * 4 + qd) ^ l7) * 8)];
        acc[nd] = MFMA(pa[js], bv, acc[nd]);
      }
    }
  }

  // direct f16 store (disjoint per z) — no atomics
#pragma unroll
  for (int nd = 0; nd < 4; nd++)
#pragma unroll
    for (int r = 0; r < 4; r++)
      Cz[(size_t)(iw + qd * 4 + r) * DIM + h * DK + nd * 16 + l16] = (f16)acc[nd][r];
}

// ---------------------------------------------------------------- launcher
extern "C" void kernel_launch(void* const* d_in, const int* in_sizes, int n_in,
                              void* d_out, int out_size, void* d_ws, size_t ws_size,
                              hipStream_t stream) {
  const float* q  = (const float*)d_in[0];
  const float* k  = (const float*)d_in[1];
  const float* v  = (const float*)d_in[2];
  const float* Wq = (const float*)d_in[3];
  const float* bq = (const float*)d_in[4];
  const float* Wk = (const float*)d_in[5];
  const float* bk = (const float*)d_in[6];
  const float* Wv = (const float*)d_in[7];
  const float* bv = (const float*)d_in[8];
  const float* Wo = (const float*)d_in[9];
  const float* bo = (const float*)d_in[10];
  float* out = (float*)d_out;

  f16* w = (f16*)d_ws;
  f16* qh  = w;                          // 0..4MB
  f16* kh  = qh + (size_t)S_LEN * DIM;   // 4..8
  f16* vh  = kh + (size_t)S_LEN * DIM;   // 8..12
  f16* wqh = vh + (size_t)S_LEN * DIM;   // 12..14
  f16* wkh = wqh + (size_t)DIM * DIM;    // 14..16
  f16* wvh = wkh + (size_t)DIM * DIM;    // 16..18
  f16* woh = wvh + (size_t)DIM * DIM;    // 18..20
  f16* Qp  = woh + (size_t)DIM * DIM;    // 20..24
  f16* Kp  = Qp + (size_t)S_LEN * DIM;   // 24..28
  f16* Vt  = Kp + (size_t)S_LEN * DIM;   // 28..32
  f16* IDn = qh;                         // 0..8MB  [qh/kh dead after gemm_qkv]
  f16* C0  = vh;                         // 8..12MB [vh dead after gemm_qkv]
  f16* C1  = wqh;                        // 12..16MB [wqh/wkh dead]
  f16* Ct  = qh;                         // 0..4MB  [IDn dead after attn_ctx]

  dim3 b256(256);
  cvt_all<<<dim3(1024, 10), b256, 0, stream>>>(q, k, v, Wq, Wk, Wv, Wo,
                                               qh, kh, vh, wqh, wkh, wvh, woh);

  gemm_qkv<<<dim3(DIM / 64, S_LEN / 128, 3), b256, 0, stream>>>(
      qh, kh, vh, wqh, wkh, wvh, bq, bk, bv, Qp, Kp, Vt);

  attn_denom<<<dim3(S_LEN / 64, S_LEN / 64), b256, 0, stream>>>(Qp, Kp, IDn);
  attn_ctx<<<dim3(S_LEN / 64, NH, 2), b256, 0, stream>>>(Qp, Kp, Vt, IDn, C0, C1);

  const int n8 = S_LEN * DIM / 8;
  sum_halves<<<n8 / 256, b256, 0, stream>>>(C0, C1, Ct);

  gemm_out<<<dim3(DIM / 64, S_LEN / 64), b256, 0, stream>>>(Ct, woh, bo, out);
}

// Round 11
// 192.175 us; speedup vs baseline: 1.2981x; 1.0679x over previous
//
#include <hip/hip_runtime.h>
#include <hip/hip_fp16.h>

// MHA with softmax over HEADS axis. R18: apply R17's validated mechanism
// (halve per-iteration fixed cost at unchanged occupancy) to both GEMMs.
// gemm_qkv: BK=64 gemm64_core, 16 iters, R17's 3-bit XOR slot swizzle on the
// 128B-row LDS tiles (source-swizzled gload + XOR'd read). gemm_out: BK=64
// AND fused sum (A = C0+C1 staged via regs, f32 add = sum_halves math, write-
// side swizzle + lgkmcnt(0) before barrier) -> sum_halves kernel eliminated.
// ctx/denom unchanged from R17. All accumulation orders preserved.

typedef _Float16 f16;
typedef _Float16 f16x4 __attribute__((ext_vector_type(4)));
typedef _Float16 f16x8 __attribute__((ext_vector_type(8)));
typedef float    f32x4 __attribute__((ext_vector_type(4)));

#define S_LEN 2048
#define DIM   1024
#define NH    16
#define DK    64
// exp(s * 0.125) = exp2(s * log2(e)/8)
#define EXP2K 0.1803368801111244f

#define MFMA(a, b, c) __builtin_amdgcn_mfma_f32_16x16x32_f16(a, b, c, 0, 0, 0)

#define VM_WAIT0   asm volatile("s_waitcnt vmcnt(0)" ::: "memory")
#define LGKM_WAIT0 asm volatile("s_waitcnt lgkmcnt(0)" ::: "memory")
#define WG_BARRIER asm volatile("s_barrier" ::: "memory")

typedef __attribute__((address_space(1))) void g_void;
typedef __attribute__((address_space(3))) void l_void;

static __device__ __forceinline__ void gload_lds16(const void* g, void* l) {
  __builtin_amdgcn_global_load_lds((g_void*)g, (l_void*)l, 16, 0, 0);
}

static __device__ __forceinline__ float exp_s(float s) {
  return __builtin_amdgcn_exp2f(s * EXP2K);  // identical in denom & ctx
}

// ---------------------------------------------------------------- merged cvt fp32->f16
__global__ __launch_bounds__(256) void cvt_all(
    const float* __restrict__ q, const float* __restrict__ k, const float* __restrict__ v,
    const float* __restrict__ Wq, const float* __restrict__ Wk, const float* __restrict__ Wv,
    const float* __restrict__ Wo, f16* __restrict__ qh, f16* __restrict__ kh,
    f16* __restrict__ vh, f16* __restrict__ wqh, f16* __restrict__ wkh,
    f16* __restrict__ wvh, f16* __restrict__ woh) {
  const size_t M = 1048576;
  const int seg = blockIdx.y;
  const float* src;
  f16* dst;
  switch (seg) {
    case 0: src = q;      dst = qh;      break;
    case 1: src = q + M;  dst = qh + M;  break;
    case 2: src = k;      dst = kh;      break;
    case 3: src = k + M;  dst = kh + M;  break;
    case 4: src = v;      dst = vh;      break;
    case 5: src = v + M;  dst = vh + M;  break;
    case 6: src = Wq;     dst = wqh;     break;
    case 7: src = Wk;     dst = wkh;     break;
    case 8: src = Wv;     dst = wvh;     break;
    default: src = Wo;    dst = woh;     break;
  }
  int i = blockIdx.x * 256 + threadIdx.x;
  float4 vv = ((const float4*)src)[i];
  f16x4 o = {(f16)vv.x, (f16)vv.y, (f16)vv.z, (f16)vv.w};
  ((f16x4*)dst)[i] = o;
}

// ---------------------------------------------------------------- BK=64 pipelined 128x64 core
// As:[2][128*64] Bs:[2][64*64] (48KB), 3-bit XOR slot swizzle (R17-verified):
// source col slot lc8^lr8, linear gload dest, read slot ((kk*4+qd)^(row&7)).
static __device__ __forceinline__ void gemm64_core(const f16* __restrict__ X,
                                                   const f16* __restrict__ W,
                                                   int bm, int bn,
                                                   f16* As, f16* Bs,
                                                   f32x4 (&acc)[4][2]) {
  const int tid = threadIdx.x;
  const int wv = tid >> 6;
  const int lane = tid & 63;
  const int qd = lane >> 4;
  const int l16 = lane & 15;
  const int wm = (wv & 1) * 64;
  const int wn = (wv >> 1) * 32;
  const int lr8 = lane >> 3, lc8 = lane & 7;
  const int l7 = l16 & 7;

  const f16* gA = X + (size_t)(bm + wv * 32 + lr8) * DIM + (lc8 ^ lr8) * 8;
  const f16* gB = W + (size_t)(bn + wv * 16 + lr8) * DIM + (lc8 ^ lr8) * 8;

  auto issue = [&](int t, f16* dA, f16* dB) {
#pragma unroll
    for (int g = 0; g < 4; g++)
      gload_lds16(gA + (size_t)(g * 8) * DIM + t * 64, dA + (wv * 32 + g * 8) * 64);
#pragma unroll
    for (int g = 0; g < 2; g++)
      gload_lds16(gB + (size_t)(g * 8) * DIM + t * 64, dB + (wv * 16 + g * 8) * 64);
  };

  issue(0, As, Bs);

#pragma unroll 2
  for (int t = 0; t < 16; t++) {
    const int buf = t & 1;
    VM_WAIT0;
    WG_BARRIER;
    if (t + 1 < 16)
      issue(t + 1, As + (buf ^ 1) * (128 * 64), Bs + (buf ^ 1) * (64 * 64));
    const f16* A = As + buf * (128 * 64);
    const f16* B = Bs + buf * (64 * 64);
#pragma unroll
    for (int kk = 0; kk < 2; kk++) {
      const int slot = ((kk * 4 + qd) ^ l7) * 8;
      f16x8 bf[2];
#pragma unroll
      for (int ni = 0; ni < 2; ni++)
        bf[ni] = *(const f16x8*)&B[(wn + ni * 16 + l16) * 64 + slot];
#pragma unroll
      for (int mi = 0; mi < 4; mi++) {
        f16x8 af = *(const f16x8*)&A[(wm + mi * 16 + l16) * 64 + slot];
#pragma unroll
        for (int ni = 0; ni < 2; ni++)
          acc[mi][ni] = MFMA(af, bf[ni], acc[mi][ni]);
      }
    }
  }
}

// ---------------------------------------------------------------- merged QKV proj
__global__ __launch_bounds__(256) void gemm_qkv(
    const f16* __restrict__ X0, const f16* __restrict__ X1, const f16* __restrict__ X2,
    const f16* __restrict__ W0, const f16* __restrict__ W1, const f16* __restrict__ W2,
    const float* __restrict__ b0, const float* __restrict__ b1, const float* __restrict__ b2,
    f16* __restrict__ o0, f16* __restrict__ o1, f16* __restrict__ o2) {
  __shared__ __align__(16) f16 As[2 * 128 * 64];  // 32KB
  __shared__ __align__(16) f16 Bs[2 * 64 * 64];   // 16KB
  const int z = blockIdx.z;
  const f16* X = z == 0 ? X0 : z == 1 ? X1 : X2;
  const f16* W = z == 0 ? W0 : z == 1 ? W1 : W2;
  const float* bias = z == 0 ? b0 : z == 1 ? b1 : b2;
  f16* outh = z == 0 ? o0 : z == 1 ? o1 : o2;

  const int bm = blockIdx.y * 128, bn = blockIdx.x * 64;
  f32x4 acc[4][2];
#pragma unroll
  for (int a = 0; a < 4; a++)
#pragma unroll
    for (int b = 0; b < 2; b++) acc[a][b] = (f32x4){0.f, 0.f, 0.f, 0.f};

  gemm64_core(X, W, bm, bn, As, Bs, acc);

  const int tid = threadIdx.x;
  const int wv = tid >> 6, lane = tid & 63;
  const int qd = lane >> 4, l16 = lane & 15;
  const int wm = (wv & 1) * 64, wn = (wv >> 1) * 32;
#pragma unroll
  for (int mi = 0; mi < 4; mi++) {
#pragma unroll
    for (int ni = 0; ni < 2; ni++) {
      const int gm = bm + wm + mi * 16 + qd * 4;
      const int gn = bn + wn + ni * 16 + l16;
      const float bs = bias[gn];
      if (z == 2) {
        f16x4 o = {(f16)(acc[mi][ni][0] + bs), (f16)(acc[mi][ni][1] + bs),
                   (f16)(acc[mi][ni][2] + bs), (f16)(acc[mi][ni][3] + bs)};
        // Vt stored j-PERMUTED within each 32-block: storage[pi(j)] = V[j],
        // pi(gm) = (gm&~31) + ((gm>>2)&3)*8 + ((gm>>4)&1)*4 + (gm&3).
        const int pj = (gm & ~31) + ((gm >> 2) & 3) * 8 + ((gm >> 4) & 1) * 4;
        *(f16x4*)&outh[(size_t)gn * S_LEN + pj] = o;  // Vt[d][perm j]
      } else {
#pragma unroll
        for (int r = 0; r < 4; r++)
          outh[(size_t)(gm + r) * DIM + gn] = (f16)(acc[mi][ni][r] + bs);
      }
    }
  }
}

// ---------------------------------------------------------------- out GEMM 64x64, BK=64,
// fused A = C0 + C1 (reg-staged, f32 add == sum_halves math, write-side
// swizzle + lgkmcnt(0) before barrier). B via source-swizzled gload_lds.
// Direct f32 store + bias. grid (16,32) = 512 blocks = 2/CU.
__global__ __launch_bounds__(256) void gemm_out(const f16* __restrict__ C0,
                                                const f16* __restrict__ C1,
                                                const f16* __restrict__ W,
                                                const float* __restrict__ bias,
                                                float* __restrict__ outf) {
  __shared__ __align__(16) f16 As[2 * 64 * 64];  // 16KB
  __shared__ __align__(16) f16 Bs[2 * 64 * 64];  // 16KB
  const int tid = threadIdx.x;
  const int wv = tid >> 6;
  const int lane = tid & 63;
  const int qd = lane >> 4;
  const int l16 = lane & 15;
  const int wm = (wv & 1) * 32;
  const int wn = (wv >> 1) * 32;
  const int lr8 = lane >> 3, lc8 = lane & 7;
  const int l7 = l16 & 7;
  const int bm = blockIdx.y * 64, bn = blockIdx.x * 64;

  const f16* gA0 = C0 + (size_t)(bm + wv * 16 + lr8) * DIM + lc8 * 8;
  const f16* gA1 = C1 + (size_t)(bm + wv * 16 + lr8) * DIM + lc8 * 8;
  const f16* gB  = W + (size_t)(bn + wv * 16 + lr8) * DIM + (lc8 ^ lr8) * 8;

  f16x8 a0[2], a1[2];
  auto issueA = [&](int t) {
#pragma unroll
    for (int g = 0; g < 2; g++) {
      a0[g] = *(const f16x8*)(gA0 + (size_t)(g * 8) * DIM + t * 64);
      a1[g] = *(const f16x8*)(gA1 + (size_t)(g * 8) * DIM + t * 64);
    }
  };
  auto issueB = [&](int t, f16* dB) {
#pragma unroll
    for (int g = 0; g < 2; g++)
      gload_lds16(gB + (size_t)(g * 8) * DIM + t * 64, dB + (wv * 16 + g * 8) * 64);
  };

  f32x4 acc[2][2];
#pragma unroll
  for (int a = 0; a < 2; a++)
#pragma unroll
    for (int b = 0; b < 2; b++) acc[a][b] = (f32x4){0.f, 0.f, 0.f, 0.f};

  issueA(0);
  issueB(0, Bs);

#pragma unroll 2
  for (int t = 0; t < 16; t++) {
    const int buf = t & 1;
    VM_WAIT0;  // a0/a1 regs + B gload_lds for tile t landed
    // A = C0 + C1 (f32 math, identical to sum_halves), write-side swizzle
    f16* Ab = As + buf * (64 * 64);
#pragma unroll
    for (int g = 0; g < 2; g++) {
      f16x8 s;
#pragma unroll
      for (int j = 0; j < 8; j++) s[j] = (f16)((float)a0[g][j] + (float)a1[g][j]);
      *(f16x8*)&Ab[(wv * 16 + g * 8 + lr8) * 64 + (lc8 ^ lr8) * 8] = s;
    }
    LGKM_WAIT0;  // own ds_writes drained before barrier
    WG_BARRIER;
    if (t + 1 < 16) {
      issueA(t + 1);
      issueB(t + 1, Bs + (buf ^ 1) * (64 * 64));
    }
    const f16* A = Ab;
    const f16* B = Bs + buf * (64 * 64);
#pragma unroll
    for (int kk = 0; kk < 2; kk++) {
      const int slot = ((kk * 4 + qd) ^ l7) * 8;
      f16x8 bf[2], af[2];
#pragma unroll
      for (int ni = 0; ni < 2; ni++)
        bf[ni] = *(const f16x8*)&B[(wn + ni * 16 + l16) * 64 + slot];
#pragma unroll
      for (int mi = 0; mi < 2; mi++)
        af[mi] = *(const f16x8*)&A[(wm + mi * 16 + l16) * 64 + slot];
#pragma unroll
      for (int mi = 0; mi < 2; mi++)
#pragma unroll
        for (int ni = 0; ni < 2; ni++)
          acc[mi][ni] = MFMA(af[mi], bf[ni], acc[mi][ni]);
    }
  }

#pragma unroll
  for (int mi = 0; mi < 2; mi++) {
#pragma unroll
    for (int ni = 0; ni < 2; ni++) {
      const int gm = bm + wm + mi * 16 + qd * 4;
      const int gn = bn + wn + ni * 16 + l16;
      const float bs = bias[gn];
#pragma unroll
      for (int r = 0; r < 4; r++)
        outf[(size_t)(gm + r) * DIM + gn] = acc[mi][ni][r] + bs;
    }
  }
}

// ---------------------------------------------------------------- pass A: IDn = 1/sum_h exp
// 64x64 tile, grid 1024, XCD-remapped (4 bi-tiles x all bj per XCD). IDn
// stored j-PERMUTED (same pi as Vt). Qs/Ks reads conflict-free via both-sides
// XOR slot swizzle -- bit-identical values.
__global__ __launch_bounds__(256) void attn_denom(const f16* __restrict__ Qp,
                                                  const f16* __restrict__ Kp,
                                                  f16* __restrict__ IDn) {
  __shared__ __align__(16) f16 Qs[2][2][64 * 32];  // [buf][kk][row][32]
  __shared__ __align__(16) f16 Ks[2][2][64 * 32];
  const int tid = threadIdx.x;
  const int wv = tid >> 6;
  const int lane = tid & 63;
  const int qd = lane >> 4;
  const int l16 = lane & 15;
  const int wm = (wv & 1) * 32, wn = (wv >> 1) * 32;
  // XCD remap: xcd = flat&7 owns nf in [xcd*128, xcd*128+128) = 4 bi-tiles
  // x all 32 bj -> 128 co-resident blocks/XCD share K tiles x4, Q x32 in L2.
  const int flat = blockIdx.x + (blockIdx.y << 5);
  const int nf = ((flat & 7) << 7) + (flat >> 3);
  const int bi = (nf >> 5) * 64, bj = (nf & 31) * 64;
  const int lr4 = lane >> 2, lc4 = lane & 3;
  const int kkw = wv & 1;
  const int q0 = (wv >> 1) * 2;
  const int ssw = (lc4 ^ ((lr4 >> 1) & 3)) * 8;  // swizzled source col slot
  const int rsw = (qd ^ ((l16 >> 1) & 3)) * 8;   // swizzled read slot

  f32x4 dsum[2][2];
#pragma unroll
  for (int a = 0; a < 2; a++)
#pragma unroll
    for (int b = 0; b < 2; b++) dsum[a][b] = (f32x4){0.f, 0.f, 0.f, 0.f};

  // prologue: head 0 -> buf 0
  {
    const f16* gq = Qp + (size_t)(bi + q0 * 16 + lr4) * DIM + kkw * 32 + ssw;
    const f16* gk = Kp + (size_t)(bj + q0 * 16 + lr4) * DIM + kkw * 32 + ssw;
#pragma unroll
    for (int t = 0; t < 2; t++) {
      gload_lds16(gq + (size_t)t * 16 * DIM, &Qs[0][kkw][(q0 + t) * 16 * 32]);
      gload_lds16(gk + (size_t)t * 16 * DIM, &Ks[0][kkw][(q0 + t) * 16 * 32]);
    }
  }

#pragma unroll 2
  for (int h = 0; h < NH; h++) {
    const int buf = h & 1;
    VM_WAIT0;
    WG_BARRIER;
    if (h + 1 < NH) {
      const f16* gq = Qp + (size_t)(bi + q0 * 16 + lr4) * DIM + (h + 1) * DK + kkw * 32 + ssw;
      const f16* gk = Kp + (size_t)(bj + q0 * 16 + lr4) * DIM + (h + 1) * DK + kkw * 32 + ssw;
#pragma unroll
      for (int t = 0; t < 2; t++) {
        gload_lds16(gq + (size_t)t * 16 * DIM, &Qs[buf ^ 1][kkw][(q0 + t) * 16 * 32]);
        gload_lds16(gk + (size_t)t * 16 * DIM, &Ks[buf ^ 1][kkw][(q0 + t) * 16 * 32]);
      }
    }

#pragma unroll
    for (int mi = 0; mi < 2; mi++) {
      f16x8 af0 = *(const f16x8*)&Qs[buf][0][(wm + mi * 16 + l16) * 32 + rsw];
      f16x8 af1 = *(const f16x8*)&Qs[buf][1][(wm + mi * 16 + l16) * 32 + rsw];
#pragma unroll
      for (int ni = 0; ni < 2; ni++) {
        f16x8 bf0 = *(const f16x8*)&Ks[buf][0][(wn + ni * 16 + l16) * 32 + rsw];
        f16x8 bf1 = *(const f16x8*)&Ks[buf][1][(wn + ni * 16 + l16) * 32 + rsw];
        f32x4 s = {0.f, 0.f, 0.f, 0.f};
        s = MFMA(af0, bf0, s);  // kk order identical to attn_ctx
        s = MFMA(af1, bf1, s);
#pragma unroll
        for (int r = 0; r < 4; r++) dsum[mi][ni][r] += exp_s(s[r]);
      }
    }
  }
#pragma unroll
  for (int mi = 0; mi < 2; mi++)
#pragma unroll
    for (int ni = 0; ni < 2; ni++)
#pragma unroll
      for (int r = 0; r < 4; r++) {
        const int gi = bi + wm + mi * 16 + qd * 4 + r;
        const int gj = bj + wn + ni * 16 + l16;
        // j-permuted store (same pi as Vt): IDnP[pi(gj)] = 1/dsum(gj)
        const int pj = (gj & ~31) + ((gj >> 2) & 3) * 8 + ((gj >> 4) & 1) * 4 + (gj & 3);
        IDn[(size_t)gi * S_LEN + pj] = (f16)(1.f / dsum[mi][ni][r]);
      }
}

// ---------------------------------------------------------------- pass B: ctx
// grid (32, 16, 2) = 1024 blocks = 4/CU. KVBLK=64: 16 iterations, 16 MFMA/
// iter. K: 2-bit XOR swizzle; V 64x64 (128B rows): 3-bit XOR slot swizzle.
// Direct f16 stores to disjoint half-buffers. (R17-verified, unchanged.)
__global__ __launch_bounds__(256, 4) void attn_ctx(const f16* __restrict__ Qp,
                                                   const f16* __restrict__ Kp,
                                                   const f16* __restrict__ Vt,
                                                   const f16* __restrict__ IDn,
                                                   f16* __restrict__ C0,
                                                   f16* __restrict__ C1) {
  __shared__ __align__(16) f16 Ks[2][2][64 * 32];  // [buf][kk][j64][dk32] 16KB
  __shared__ __align__(16) f16 Vs[2][64 * 64];     // [buf][d64][j64 perm]  16KB
  const int tid = threadIdx.x;
  const int wv = tid >> 6;
  const int lane = tid & 63;
  const int qd = lane >> 4;
  const int l16 = lane & 15;
  // XCD-aware remap over flat 1024: 128-block chunks/XCD.
  const int flat = blockIdx.x + (blockIdx.y << 5) + (blockIdx.z << 9);
  const int nf = ((flat & 7) << 7) + (flat >> 3);
  const int h = (nf >> 5) & 15;
  const int iw = (nf & 31) * 64 + wv * 16;
  const int z = nf >> 9;
  const int jb = z * 1024;
  f16* Cz = z == 0 ? C0 : C1;
  const int lr4 = lane >> 2, lc4 = lane & 3;
  const int lr8 = lane >> 3, lc8 = lane & 7;
  const int kkw = wv & 1;
  const int rhw = wv >> 1;
  const int ssw = (lc4 ^ ((lr4 >> 1) & 3)) * 8;  // K: swizzled source col slot
  const int rsw = (qd ^ ((l16 >> 1) & 3)) * 8;   // K: swizzled read slot
  const int l7 = l16 & 7;                        // V: 3-bit row XOR key

  // Q fragment (B-operand of swapped QK^T), 1 mi
  f16x8 aq[2];
#pragma unroll
  for (int kk = 0; kk < 2; kk++)
    aq[kk] = *(const f16x8*)(Qp + (size_t)(iw + l16) * DIM + h * DK + kk * 32 + qd * 8);

  f32x4 acc[4];
#pragma unroll
  for (int b = 0; b < 4; b++) acc[b] = (f32x4){0.f, 0.f, 0.f, 0.f};

  f16x8 idn[2][2];  // [buf][js] permuted-IDn, elementwise aligned with P

  // one group = 6 vmem ops/wave: 2 K gload + 2 V gload + 2 idn f16x8
  auto issue = [&](int tt, int pb) {
    const int j1 = jb + tt * 64;
    const f16* gk = Kp + (size_t)(j1 + rhw * 16 + lr4) * DIM + h * DK + kkw * 32 + ssw;
    gload_lds16(gk, &Ks[pb][kkw][(rhw * 16) * 32]);
    gload_lds16(gk + (size_t)32 * DIM, &Ks[pb][kkw][(rhw * 16 + 32) * 32]);
    // V: dest linear; source slot XOR'd by (d&7)=lr8 (3-bit, both gloads)
    const f16* gv = Vt + (size_t)(h * DK + wv * 16 + lr8) * S_LEN + j1 + (lc8 ^ lr8) * 8;
    gload_lds16(gv, &Vs[pb][(wv * 16) * 64]);
    gload_lds16(gv + (size_t)8 * S_LEN, &Vs[pb][(wv * 16 + 8) * 64]);
#pragma unroll
    for (int js = 0; js < 2; js++)
      idn[pb][js] = *(const f16x8*)(IDn + (size_t)(iw + l16) * S_LEN + j1 + js * 32 + qd * 8);
  };

  issue(0, 0);

#pragma unroll 2
  for (int t = 0; t < 16; t++) {
    const int buf = t & 1;
    VM_WAIT0;
    WG_BARRIER;
    if (t + 1 < 16) issue(t + 1, buf ^ 1);

    // per js-subblock: QK^T (swapped) + exp + permuted-IDn scale, lane-local
    f16x8 pa[2];
#pragma unroll
    for (int js = 0; js < 2; js++) {
      f16x8 bk0[2], bk1[2];  // ni = js*2, js*2+1
#pragma unroll
      for (int kk = 0; kk < 2; kk++) {
        bk0[kk] = *(const f16x8*)&Ks[buf][kk][((js * 2) * 16 + l16) * 32 + rsw];
        bk1[kk] = *(const f16x8*)&Ks[buf][kk][((js * 2 + 1) * 16 + l16) * 32 + rsw];
      }
      f32x4 st0 = {0.f, 0.f, 0.f, 0.f};
      f32x4 st1 = {0.f, 0.f, 0.f, 0.f};
      st0 = MFMA(bk0[0], aq[0], st0);  // kk order identical to attn_denom
      st0 = MFMA(bk0[1], aq[1], st0);
      st1 = MFMA(bk1[0], aq[0], st1);
      st1 = MFMA(bk1[1], aq[1], st1);
      f16x8 p;
#pragma unroll
      for (int r = 0; r < 4; r++) p[r] = (f16)(exp_s(st0[r]) * (float)idn[buf][js][r]);
#pragma unroll
      for (int r = 0; r < 4; r++) p[4 + r] = (f16)(exp_s(st1[r]) * (float)idn[buf][js][4 + r]);
      pa[js] = p;
    }

    // PV: B-operand b128 from permuted Vs; read slot (js*4+qd) ^ (row&7)
#pragma unroll
    for (int js = 0; js < 2; js++) {
#pragma unroll
      for (int nd = 0; nd < 4; nd++) {
        f16x8 bv = *(const f16x8*)&Vs[buf][(nd * 16 + l16) * 64 +
                                          (((js * 4 + qd) ^ l7) * 8)];
        acc[nd] = MFMA(pa[js], bv, acc[nd]);
      }
    }
  }

  // direct f16 store (disjoint per z) — no atomics
#pragma unroll
  for (int nd = 0; nd < 4; nd++)
#pragma unroll
    for (int r = 0; r < 4; r++)
      Cz[(size_t)(iw + qd * 4 + r) * DIM + h * DK + nd * 16 + l16] = (f16)acc[nd][r];
}

// ---------------------------------------------------------------- launcher
extern "C" void kernel_launch(void* const* d_in, const int* in_sizes, int n_in,
                              void* d_out, int out_size, void* d_ws, size_t ws_size,
                              hipStream_t stream) {
  const float* q  = (const float*)d_in[0];
  const float* k  = (const float*)d_in[1];
  const float* v  = (const float*)d_in[2];
  const float* Wq = (const float*)d_in[3];
  const float* bq = (const float*)d_in[4];
  const float* Wk = (const float*)d_in[5];
  const float* bk = (const float*)d_in[6];
  const float* Wv = (const float*)d_in[7];
  const float* bv = (const float*)d_in[8];
  const float* Wo = (const float*)d_in[9];
  const float* bo = (const float*)d_in[10];
  float* out = (float*)d_out;

  f16* w = (f16*)d_ws;
  f16* qh  = w;                          // 0..4MB
  f16* kh  = qh + (size_t)S_LEN * DIM;   // 4..8
  f16* vh  = kh + (size_t)S_LEN * DIM;   // 8..12
  f16* wqh = vh + (size_t)S_LEN * DIM;   // 12..14
  f16* wkh = wqh + (size_t)DIM * DIM;    // 14..16
  f16* wvh = wkh + (size_t)DIM * DIM;    // 16..18
  f16* woh = wvh + (size_t)DIM * DIM;    // 18..20
  f16* Qp  = woh + (size_t)DIM * DIM;    // 20..24
  f16* Kp  = Qp + (size_t)S_LEN * DIM;   // 24..28
  f16* Vt  = Kp + (size_t)S_LEN * DIM;   // 28..32
  f16* IDn = qh;                         // 0..8MB  [qh/kh dead after gemm_qkv]
  f16* C0  = vh;                         // 8..12MB [vh dead after gemm_qkv]
  f16* C1  = wqh;                        // 12..16MB [wqh/wkh dead]

  dim3 b256(256);
  cvt_all<<<dim3(1024, 10), b256, 0, stream>>>(q, k, v, Wq, Wk, Wv, Wo,
                                               qh, kh, vh, wqh, wkh, wvh, woh);

  gemm_qkv<<<dim3(DIM / 64, S_LEN / 128, 3), b256, 0, stream>>>(
      qh, kh, vh, wqh, wkh, wvh, bq, bk, bv, Qp, Kp, Vt);

  attn_denom<<<dim3(S_LEN / 64, S_LEN / 64), b256, 0, stream>>>(Qp, Kp, IDn);
  attn_ctx<<<dim3(S_LEN / 64, NH, 2), b256, 0, stream>>>(Qp, Kp, Vt, IDn, C0, C1);

  gemm_out<<<dim3(DIM / 64, S_LEN / 64), b256, 0, stream>>>(C0, C1, woh, bo, out);
}